// Round 1
// baseline (1424.748 us; speedup 1.0000x reference)
//
#include <hip/hip_runtime.h>

#define T_SEQ 1024
#define DH 64
#define NH 8
#define NB 2
#define EMB 512

__device__ __forceinline__ int swz4(int r, int c4) {
    // float4-granular XOR swizzle for 64x64 f32 tiles stored as float4[64*16]
    return r * 16 + ((c4 ^ (r >> 2)) & 15);
}

__device__ __forceinline__ void fma4(float4& o, float s, const float4& b) {
    o.x += s * b.x; o.y += s * b.y; o.z += s * b.z; o.w += s * b.w;
}

// ---------------------------------------------------------------------------
// Stage 1: q/k/v = x @ W{q,k,v}, written as [B,H,T,d] per-head layout.
// ---------------------------------------------------------------------------
__global__ __launch_bounds__(256) void proj_gemm(
    const float* __restrict__ x, const float* __restrict__ Wq,
    const float* __restrict__ Wk, const float* __restrict__ Wv,
    float* __restrict__ q, float* __restrict__ k, float* __restrict__ v) {
    const float* W = (blockIdx.z == 0) ? Wq : (blockIdx.z == 1) ? Wk : Wv;
    float* out = (blockIdx.z == 0) ? q : (blockIdx.z == 1) ? k : v;
    int bm = blockIdx.x, bn = blockIdx.y;
    int tid = threadIdx.x;
    int tx = tid & 15, ty = tid >> 4;

    __shared__ float As[16 * 64];   // [k][m]
    __shared__ float4 Bs[16 * 16];  // [k][n4]

    float4 acc[4];
    acc[0] = acc[1] = acc[2] = acc[3] = make_float4(0.f, 0.f, 0.f, 0.f);

    int ar = tid >> 2, ak4 = tid & 3;
    int bkr = tid >> 4, bn4 = tid & 15;
    const float* Aptr = x + (size_t)(bm * 64 + ar) * EMB + ak4 * 4;
    const float* Bptr = W + (size_t)bkr * EMB + bn * 64 + bn4 * 4;

    for (int k0 = 0; k0 < EMB; k0 += 16) {
        float4 a = *(const float4*)(Aptr + k0);
        float4 b = *(const float4*)(Bptr + (size_t)k0 * EMB);
        __syncthreads();
        As[(ak4 * 4 + 0) * 64 + ar] = a.x;
        As[(ak4 * 4 + 1) * 64 + ar] = a.y;
        As[(ak4 * 4 + 2) * 64 + ar] = a.z;
        As[(ak4 * 4 + 3) * 64 + ar] = a.w;
        Bs[bkr * 16 + bn4] = b;
        __syncthreads();
#pragma unroll
        for (int kk = 0; kk < 16; ++kk) {
            float4 a4 = ((const float4*)As)[kk * 16 + ty];
            float4 b4 = Bs[kk * 16 + tx];
            fma4(acc[0], a4.x, b4);
            fma4(acc[1], a4.y, b4);
            fma4(acc[2], a4.z, b4);
            fma4(acc[3], a4.w, b4);
        }
    }

#pragma unroll
    for (int i = 0; i < 4; ++i) {
        int mm = bm * 64 + ty * 4 + i;
        int bb = mm >> 10, t = mm & 1023;
        float* dst = out + ((size_t)(bb * NH + bn) * T_SEQ + t) * DH + tx * 4;
        *(float4*)dst = acc[i];
    }
}

// ---------------------------------------------------------------------------
// Stage 2: Sherman-Morrison scan. One wave per (b,h). Lane l owns row l of inv.
// ---------------------------------------------------------------------------
__global__ __launch_bounds__(64) void mesa_scan(
    const float* __restrict__ v, const float* __restrict__ q,
    const float* __restrict__ lambdas, float* __restrict__ preds) {
    int bh = blockIdx.x;
    int lane = threadIdx.x;
    float lam = lambdas[bh & (NH - 1)];

    float inv[64];
#pragma unroll
    for (int c = 0; c < 64; ++c) inv[c] = (c == lane) ? lam : 0.f;

    const float* vb = v + (size_t)bh * T_SEQ * DH;
    const float* qb = q + (size_t)bh * T_SEQ * DH;
    float* pb = preds + (size_t)bh * T_SEQ * DH;

    __shared__ float hxs[64];

    for (int t = 0; t < T_SEQ; ++t) {
        const float* xt = vb + t * DH;  // uniform pointer -> scalar loads
        const float* qt = qb + t * DH;
        float Hx = 0.f, Hq = 0.f;
#pragma unroll
        for (int c = 0; c < 64; ++c) {
            float xc = xt[c];
            float qc = qt[c];
            Hx += inv[c] * xc;
            Hq += inv[c] * qc;
        }
        float xv = xt[lane], qv = qt[lane];
        float p1 = xv * Hx;   // -> sum_l x[l]*Hx[l]
        float p2 = qv * Hx;   // -> sum_l q[l]*Hx[l]
#pragma unroll
        for (int off = 32; off; off >>= 1) {
            p1 += __shfl_xor(p1, off);
            p2 += __shfl_xor(p2, off);
        }
        float idn = 1.f / (1.f + p1);
        pb[(size_t)t * DH + lane] = Hq - Hx * (p2 * idn);

        hxs[lane] = Hx;
        __syncthreads();
        float coef = Hx * idn;
#pragma unroll
        for (int c4 = 0; c4 < 16; ++c4) {
            float4 h4 = ((const float4*)hxs)[c4];  // uniform broadcast read
            inv[c4 * 4 + 0] -= coef * h4.x;
            inv[c4 * 4 + 1] -= coef * h4.y;
            inv[c4 * 4 + 2] -= coef * h4.z;
            inv[c4 * 4 + 3] -= coef * h4.w;
        }
        __syncthreads();
    }
}

// ---------------------------------------------------------------------------
// Stage 3: O = tril(P @ V^T) @ K per (b,h), 64-row blocks, causal col blocks.
// ---------------------------------------------------------------------------
__global__ __launch_bounds__(256) void attn_kernel(
    const float* __restrict__ P, const float* __restrict__ V,
    const float* __restrict__ Kv, float* __restrict__ O) {
    int rb = blockIdx.x, bh = blockIdx.y;
    int tid = threadIdx.x, tx = tid & 15, ty = tid >> 4;

    __shared__ float4 Ps[64 * 16];
    __shared__ float4 Vs[64 * 16];  // reused as Ss after a barrier
    __shared__ float4 Ks[64 * 16];

    int lr = tid >> 2, lc = tid & 3;
    const float4* Pb = (const float4*)(P + ((size_t)bh * T_SEQ + rb * 64) * DH);
#pragma unroll
    for (int i = 0; i < 4; ++i)
        Ps[swz4(lr, lc + i * 4)] = Pb[lr * 16 + lc + i * 4];

    float4 o[4];
    o[0] = o[1] = o[2] = o[3] = make_float4(0.f, 0.f, 0.f, 0.f);
    __syncthreads();

    for (int cb = 0; cb <= rb; ++cb) {
        const float4* Vb = (const float4*)(V + ((size_t)bh * T_SEQ + cb * 64) * DH);
        const float4* Kb = (const float4*)(Kv + ((size_t)bh * T_SEQ + cb * 64) * DH);
#pragma unroll
        for (int i = 0; i < 4; ++i) {
            Vs[swz4(lr, lc + i * 4)] = Vb[lr * 16 + lc + i * 4];
            Ks[swz4(lr, lc + i * 4)] = Kb[lr * 16 + lc + i * 4];
        }
        __syncthreads();

        // S[m][j] = sum_d P[m][d] * V[j][d]
        float4 sa[4][4];
#pragma unroll
        for (int i = 0; i < 4; ++i)
#pragma unroll
            for (int j = 0; j < 4; ++j) sa[i][j] = make_float4(0.f, 0.f, 0.f, 0.f);
#pragma unroll
        for (int d4 = 0; d4 < 16; ++d4) {
            float4 a[4], b[4];
#pragma unroll
            for (int i = 0; i < 4; ++i) a[i] = Ps[swz4(ty * 4 + i, d4)];
#pragma unroll
            for (int j = 0; j < 4; ++j) b[j] = Vs[swz4(tx * 4 + j, d4)];
#pragma unroll
            for (int i = 0; i < 4; ++i)
#pragma unroll
                for (int j = 0; j < 4; ++j) {
                    sa[i][j].x += a[i].x * b[j].x;
                    sa[i][j].y += a[i].y * b[j].y;
                    sa[i][j].z += a[i].z * b[j].z;
                    sa[i][j].w += a[i].w * b[j].w;
                }
        }
        __syncthreads();  // all Vs reads done before overwriting with S

        bool diag = (cb == rb);
#pragma unroll
        for (int i = 0; i < 4; ++i) {
            int m = ty * 4 + i;
            float sv[4];
#pragma unroll
            for (int j = 0; j < 4; ++j) {
                float s = sa[i][j].x + sa[i][j].y + sa[i][j].z + sa[i][j].w;
                if (diag && (tx * 4 + j) > m) s = 0.f;
                sv[j] = s;
            }
            Vs[swz4(m, tx)] = make_float4(sv[0], sv[1], sv[2], sv[3]);
        }
        __syncthreads();

        // O[m][dd] += S[m][j] * K[j][dd]
        const float* Sf = (const float*)Vs;
#pragma unroll
        for (int j = 0; j < 64; ++j) {
            float4 b4 = Ks[swz4(j, tx)];
#pragma unroll
            for (int i = 0; i < 4; ++i) {
                float s = Sf[swz4(ty * 4 + i, j >> 2) * 4 + (j & 3)];
                fma4(o[i], s, b4);
            }
        }
        __syncthreads();
    }

#pragma unroll
    for (int i = 0; i < 4; ++i) {
        float* dst = O + ((size_t)bh * T_SEQ + rb * 64 + ty * 4 + i) * DH + tx * 4;
        *(float4*)dst = o[i];
    }
}

// ---------------------------------------------------------------------------
// Stage 4: out = mesa_out.reshape(B,T,d*H) @ Wo, with (d,H)-interleave handled
// by permuting the Wo row index: row(kk) = (kk&63)*H + (kk>>6).
// ---------------------------------------------------------------------------
__global__ __launch_bounds__(256) void out_gemm(
    const float* __restrict__ A,  // attn out [B*H][T][64]
    const float* __restrict__ Wo, float* __restrict__ out) {
    int bm = blockIdx.x, bn = blockIdx.y;
    int tid = threadIdx.x;
    int tx = tid & 15, ty = tid >> 4;

    __shared__ float As[16 * 64];
    __shared__ float4 Bs[16 * 16];

    float4 acc[4];
    acc[0] = acc[1] = acc[2] = acc[3] = make_float4(0.f, 0.f, 0.f, 0.f);

    int ar = tid >> 2, ak4 = tid & 3;
    int m_ld = bm * 64 + ar;
    int b_ld = m_ld >> 10, t_ld = m_ld & 1023;
    int bkr = tid >> 4, bn4 = tid & 15;

    for (int bk = 0; bk < 32; ++bk) {
        int kkA = bk * 16 + ak4 * 4;
        int hA = kkA >> 6, ddA = kkA & 63;
        float4 a = *(const float4*)(A + ((size_t)(b_ld * NH + hA) * T_SEQ + t_ld) * DH + ddA);
        int kkB = bk * 16 + bkr;
        int hB = kkB >> 6, ddB = kkB & 63;
        float4 b = *(const float4*)(Wo + (size_t)(ddB * NH + hB) * EMB + bn * 64 + bn4 * 4);
        __syncthreads();
        As[(ak4 * 4 + 0) * 64 + ar] = a.x;
        As[(ak4 * 4 + 1) * 64 + ar] = a.y;
        As[(ak4 * 4 + 2) * 64 + ar] = a.z;
        As[(ak4 * 4 + 3) * 64 + ar] = a.w;
        Bs[bkr * 16 + bn4] = b;
        __syncthreads();
#pragma unroll
        for (int kk = 0; kk < 16; ++kk) {
            float4 a4 = ((const float4*)As)[kk * 16 + ty];
            float4 b4 = Bs[kk * 16 + tx];
            fma4(acc[0], a4.x, b4);
            fma4(acc[1], a4.y, b4);
            fma4(acc[2], a4.z, b4);
            fma4(acc[3], a4.w, b4);
        }
    }

#pragma unroll
    for (int i = 0; i < 4; ++i) {
        float* dst = out + (size_t)(bm * 64 + ty * 4 + i) * EMB + bn * 64 + tx * 4;
        *(float4*)dst = acc[i];
    }
}

extern "C" void kernel_launch(void* const* d_in, const int* in_sizes, int n_in,
                              void* d_out, int out_size, void* d_ws, size_t ws_size,
                              hipStream_t stream) {
    const float* x = (const float*)d_in[0];
    const float* Wq = (const float*)d_in[1];
    const float* Wk = (const float*)d_in[2];
    const float* Wv = (const float*)d_in[3];
    const float* Wo = (const float*)d_in[4];
    const float* lambdas = (const float*)d_in[5];
    float* out = (float*)d_out;

    float* ws = (float*)d_ws;
    const size_t SZ = (size_t)NB * NH * T_SEQ * DH;  // 1048576 floats
    float* q = ws;
    float* k = ws + SZ;
    float* v = ws + 2 * SZ;
    float* preds = ws + 3 * SZ;
    float* ao = ws + 4 * SZ;

    proj_gemm<<<dim3(32, 8, 3), 256, 0, stream>>>(x, Wq, Wk, Wv, q, k, v);
    mesa_scan<<<dim3(16), 64, 0, stream>>>(v, q, lambdas, preds);
    attn_kernel<<<dim3(16, 16), 256, 0, stream>>>(preds, v, k, ao);
    out_gemm<<<dim3(32, 8), 256, 0, stream>>>(ao, Wo, out);
}

// Round 2
// 441.455 us; speedup vs baseline: 3.2274x; 3.2274x over previous
//
#include <hip/hip_runtime.h>

#define T_SEQ 1024
#define DH 64
#define NH 8
#define NB 2
#define EMB 512
#define NCHUNK 16   // chunks per chain, chunk size = 64 tokens
#define NCHAIN 16   // B*H

__device__ __forceinline__ int swz4(int r, int c4) {
    return r * 16 + ((c4 ^ (r >> 2)) & 15);
}

__device__ __forceinline__ void fma4(float4& o, float s, const float4& b) {
    o.x += s * b.x; o.y += s * b.y; o.z += s * b.z; o.w += s * b.w;
}

// ---------------------------------------------------------------------------
// Stage 1: q/k/v = x @ W{q,k,v}, written as [B,H,T,d] per-head layout.
// ---------------------------------------------------------------------------
__global__ __launch_bounds__(256) void proj_gemm(
    const float* __restrict__ x, const float* __restrict__ Wq,
    const float* __restrict__ Wk, const float* __restrict__ Wv,
    float* __restrict__ q, float* __restrict__ k, float* __restrict__ v) {
    const float* W = (blockIdx.z == 0) ? Wq : (blockIdx.z == 1) ? Wk : Wv;
    float* out = (blockIdx.z == 0) ? q : (blockIdx.z == 1) ? k : v;
    int bm = blockIdx.x, bn = blockIdx.y;
    int tid = threadIdx.x;
    int tx = tid & 15, ty = tid >> 4;

    __shared__ float As[16 * 64];   // [k][m]
    __shared__ float4 Bs[16 * 16];  // [k][n4]

    float4 acc[4];
    acc[0] = acc[1] = acc[2] = acc[3] = make_float4(0.f, 0.f, 0.f, 0.f);

    int ar = tid >> 2, ak4 = tid & 3;
    int bkr = tid >> 4, bn4 = tid & 15;
    const float* Aptr = x + (size_t)(bm * 64 + ar) * EMB + ak4 * 4;
    const float* Bptr = W + (size_t)bkr * EMB + bn * 64 + bn4 * 4;

    for (int k0 = 0; k0 < EMB; k0 += 16) {
        float4 a = *(const float4*)(Aptr + k0);
        float4 b = *(const float4*)(Bptr + (size_t)k0 * EMB);
        __syncthreads();
        As[(ak4 * 4 + 0) * 64 + ar] = a.x;
        As[(ak4 * 4 + 1) * 64 + ar] = a.y;
        As[(ak4 * 4 + 2) * 64 + ar] = a.z;
        As[(ak4 * 4 + 3) * 64 + ar] = a.w;
        Bs[bkr * 16 + bn4] = b;
        __syncthreads();
#pragma unroll
        for (int kk = 0; kk < 16; ++kk) {
            float4 a4 = ((const float4*)As)[kk * 16 + ty];
            float4 b4 = Bs[kk * 16 + tx];
            fma4(acc[0], a4.x, b4);
            fma4(acc[1], a4.y, b4);
            fma4(acc[2], a4.z, b4);
            fma4(acc[3], a4.w, b4);
        }
    }

#pragma unroll
    for (int i = 0; i < 4; ++i) {
        int mm = bm * 64 + ty * 4 + i;
        int bb = mm >> 10, t = mm & 1023;
        float* dst = out + ((size_t)(bb * NH + bn) * T_SEQ + t) * DH + tx * 4;
        *(float4*)dst = acc[i];
    }
}

// ---------------------------------------------------------------------------
// Stage 2a: per-chunk Gram matrices G = X_chunk^T X_chunk  (64x64 per block)
// ---------------------------------------------------------------------------
__global__ __launch_bounds__(256) void gram_kernel(
    const float* __restrict__ v, float* __restrict__ g) {
    int chain = blockIdx.x, chunk = blockIdx.y;
    const float* X = v + ((size_t)chain * T_SEQ + chunk * 64) * DH;
    __shared__ float Xs[64 * 64];
    int tid = threadIdx.x;
#pragma unroll
    for (int i = 0; i < 4; ++i)
        ((float4*)Xs)[i * 256 + tid] = ((const float4*)X)[i * 256 + tid];
    __syncthreads();

    int tx = tid & 15, ty = tid >> 4;
    float acc[4][4];
#pragma unroll
    for (int i = 0; i < 4; ++i)
#pragma unroll
        for (int j = 0; j < 4; ++j) acc[i][j] = 0.f;

#pragma unroll 4
    for (int t = 0; t < 64; ++t) {
        float a_[4], b_[4];
#pragma unroll
        for (int i = 0; i < 4; ++i) a_[i] = Xs[t * 64 + ty * 4 + i];
#pragma unroll
        for (int j = 0; j < 4; ++j) b_[j] = Xs[t * 64 + tx * 4 + j];
#pragma unroll
        for (int i = 0; i < 4; ++i)
#pragma unroll
            for (int j = 0; j < 4; ++j) acc[i][j] += a_[i] * b_[j];
    }

    float* gp = g + ((size_t)chain * NCHUNK + chunk) * 4096;
#pragma unroll
    for (int i = 0; i < 4; ++i)
        *(float4*)(gp + (ty * 4 + i) * 64 + tx * 4) =
            make_float4(acc[i][0], acc[i][1], acc[i][2], acc[i][3]);
}

// ---------------------------------------------------------------------------
// Stage 2b: in-place EXCLUSIVE prefix sum of Gram matrices over the chunk axis
// ---------------------------------------------------------------------------
__global__ __launch_bounds__(256) void prefix_kernel(float* __restrict__ g) {
    int gid = blockIdx.x * 256 + threadIdx.x;
    int chain = gid >> 12, elem = gid & 4095;
    float* p = g + (size_t)chain * NCHUNK * 4096 + elem;
    float run = 0.f;
#pragma unroll
    for (int c = 0; c < NCHUNK; ++c) {
        float val = p[(size_t)c * 4096];
        p[(size_t)c * 4096] = run;
        run += val;
    }
}

// ---------------------------------------------------------------------------
// Stage 2c: H0 = (lam*I + S)^{-1} via symmetric sweep. One wave per matrix.
// Overwrites g in place with H0.
// ---------------------------------------------------------------------------
__global__ __launch_bounds__(64) void sweep_inv(
    float* __restrict__ g, const float* __restrict__ lambdas) {
    int blk = blockIdx.x;
    int chain = blk >> 4;
    int lane = threadIdx.x;
    float lam = lambdas[chain & (NH - 1)];

    float* Ap = g + (size_t)blk * 4096;
    float a[64];
#pragma unroll
    for (int c4 = 0; c4 < 16; ++c4) {
        float4 t = *(const float4*)(Ap + lane * 64 + c4 * 4);
        a[c4 * 4 + 0] = t.x; a[c4 * 4 + 1] = t.y;
        a[c4 * 4 + 2] = t.z; a[c4 * 4 + 3] = t.w;
    }
    a[lane] += lam;

    __shared__ float colbuf[64];
#pragma unroll
    for (int p = 0; p < 64; ++p) {
        colbuf[lane] = a[p];
        __syncthreads();
        float col[64];
#pragma unroll
        for (int c4 = 0; c4 < 16; ++c4) {
            float4 h = ((const float4*)colbuf)[c4];
            col[c4 * 4 + 0] = h.x; col[c4 * 4 + 1] = h.y;
            col[c4 * 4 + 2] = h.z; col[c4 * 4 + 3] = h.w;
        }
        __syncthreads();
        float ipiv = 1.f / col[p];
        if (lane == p) {
#pragma unroll
            for (int j = 0; j < 64; ++j) a[j] = col[j] * ipiv;
            a[p] = -ipiv;
        } else {
            float gc = a[p] * ipiv;
#pragma unroll
            for (int j = 0; j < 64; ++j) a[j] -= gc * col[j];
            a[p] = gc;
        }
    }

    // post-sweep a = -A^{-1}; store H0 = A^{-1}
#pragma unroll
    for (int c4 = 0; c4 < 16; ++c4)
        *(float4*)(Ap + lane * 64 + c4 * 4) =
            make_float4(-a[c4 * 4 + 0], -a[c4 * 4 + 1], -a[c4 * 4 + 2], -a[c4 * 4 + 3]);
}

// ---------------------------------------------------------------------------
// Stage 2d: Sherman-Morrison scan within each 64-token chunk, starting from H0.
// One wave per (chain, chunk); 256 independent waves.
// ---------------------------------------------------------------------------
__global__ __launch_bounds__(64) void chunk_scan(
    const float* __restrict__ v, const float* __restrict__ q,
    const float* __restrict__ g, float* __restrict__ preds) {
    int blk = blockIdx.x;
    int chain = blk >> 4, chunk = blk & 15;
    int lane = threadIdx.x;

    const float* Hp = g + (size_t)blk * 4096;
    float inv[64];
#pragma unroll
    for (int c4 = 0; c4 < 16; ++c4) {
        float4 t = *(const float4*)(Hp + lane * 64 + c4 * 4);
        inv[c4 * 4 + 0] = t.x; inv[c4 * 4 + 1] = t.y;
        inv[c4 * 4 + 2] = t.z; inv[c4 * 4 + 3] = t.w;
    }

    const float* vb = v + (size_t)chain * T_SEQ * DH;
    const float* qb = q + (size_t)chain * T_SEQ * DH;
    float* pb = preds + (size_t)chain * T_SEQ * DH;

    __shared__ float hxs[64];

    int t0 = chunk * 64;
    for (int t = t0; t < t0 + 64; ++t) {
        const float4* xt4 = (const float4*)(vb + (size_t)t * DH);
        const float4* qt4 = (const float4*)(qb + (size_t)t * DH);
        float hx0 = 0.f, hx1 = 0.f, hx2 = 0.f, hx3 = 0.f;
        float hq0 = 0.f, hq1 = 0.f, hq2 = 0.f, hq3 = 0.f;
#pragma unroll
        for (int c4 = 0; c4 < 16; ++c4) {
            float4 x4 = xt4[c4];
            float4 q4 = qt4[c4];
            hx0 += inv[c4 * 4 + 0] * x4.x; hx1 += inv[c4 * 4 + 1] * x4.y;
            hx2 += inv[c4 * 4 + 2] * x4.z; hx3 += inv[c4 * 4 + 3] * x4.w;
            hq0 += inv[c4 * 4 + 0] * q4.x; hq1 += inv[c4 * 4 + 1] * q4.y;
            hq2 += inv[c4 * 4 + 2] * q4.z; hq3 += inv[c4 * 4 + 3] * q4.w;
        }
        float Hx = (hx0 + hx1) + (hx2 + hx3);
        float Hq = (hq0 + hq1) + (hq2 + hq3);

        float xv = vb[(size_t)t * DH + lane];
        float qv = qb[(size_t)t * DH + lane];
        float p1 = xv * Hx;
        float p2 = qv * Hx;
#pragma unroll
        for (int off = 32; off; off >>= 1) {
            p1 += __shfl_xor(p1, off);
            p2 += __shfl_xor(p2, off);
        }
        float idn = 1.f / (1.f + p1);
        pb[(size_t)t * DH + lane] = Hq - Hx * (p2 * idn);

        hxs[lane] = Hx;
        __syncthreads();
        float coef = Hx * idn;
#pragma unroll
        for (int c4 = 0; c4 < 16; ++c4) {
            float4 h4 = ((const float4*)hxs)[c4];
            inv[c4 * 4 + 0] -= coef * h4.x;
            inv[c4 * 4 + 1] -= coef * h4.y;
            inv[c4 * 4 + 2] -= coef * h4.z;
            inv[c4 * 4 + 3] -= coef * h4.w;
        }
        __syncthreads();
    }
}

// ---------------------------------------------------------------------------
// Stage 3: O = tril(P @ V^T) @ K per (b,h), 64-row blocks, causal col blocks.
// ---------------------------------------------------------------------------
__global__ __launch_bounds__(256) void attn_kernel(
    const float* __restrict__ P, const float* __restrict__ V,
    const float* __restrict__ Kv, float* __restrict__ O) {
    int rb = blockIdx.x, bh = blockIdx.y;
    int tid = threadIdx.x, tx = tid & 15, ty = tid >> 4;

    __shared__ float4 Ps[64 * 16];
    __shared__ float4 Vs[64 * 16];
    __shared__ float4 Ks[64 * 16];

    int lr = tid >> 2, lc = tid & 3;
    const float4* Pb = (const float4*)(P + ((size_t)bh * T_SEQ + rb * 64) * DH);
#pragma unroll
    for (int i = 0; i < 4; ++i)
        Ps[swz4(lr, lc + i * 4)] = Pb[lr * 16 + lc + i * 4];

    float4 o[4];
    o[0] = o[1] = o[2] = o[3] = make_float4(0.f, 0.f, 0.f, 0.f);
    __syncthreads();

    for (int cb = 0; cb <= rb; ++cb) {
        const float4* Vb = (const float4*)(V + ((size_t)bh * T_SEQ + cb * 64) * DH);
        const float4* Kb = (const float4*)(Kv + ((size_t)bh * T_SEQ + cb * 64) * DH);
#pragma unroll
        for (int i = 0; i < 4; ++i) {
            Vs[swz4(lr, lc + i * 4)] = Vb[lr * 16 + lc + i * 4];
            Ks[swz4(lr, lc + i * 4)] = Kb[lr * 16 + lc + i * 4];
        }
        __syncthreads();

        float4 sa[4][4];
#pragma unroll
        for (int i = 0; i < 4; ++i)
#pragma unroll
            for (int j = 0; j < 4; ++j) sa[i][j] = make_float4(0.f, 0.f, 0.f, 0.f);
#pragma unroll
        for (int d4 = 0; d4 < 16; ++d4) {
            float4 a[4], b[4];
#pragma unroll
            for (int i = 0; i < 4; ++i) a[i] = Ps[swz4(ty * 4 + i, d4)];
#pragma unroll
            for (int j = 0; j < 4; ++j) b[j] = Vs[swz4(tx * 4 + j, d4)];
#pragma unroll
            for (int i = 0; i < 4; ++i)
#pragma unroll
                for (int j = 0; j < 4; ++j) {
                    sa[i][j].x += a[i].x * b[j].x;
                    sa[i][j].y += a[i].y * b[j].y;
                    sa[i][j].z += a[i].z * b[j].z;
                    sa[i][j].w += a[i].w * b[j].w;
                }
        }
        __syncthreads();

        bool diag = (cb == rb);
#pragma unroll
        for (int i = 0; i < 4; ++i) {
            int m = ty * 4 + i;
            float sv[4];
#pragma unroll
            for (int j = 0; j < 4; ++j) {
                float s = sa[i][j].x + sa[i][j].y + sa[i][j].z + sa[i][j].w;
                if (diag && (tx * 4 + j) > m) s = 0.f;
                sv[j] = s;
            }
            Vs[swz4(m, tx)] = make_float4(sv[0], sv[1], sv[2], sv[3]);
        }
        __syncthreads();

        const float* Sf = (const float*)Vs;
#pragma unroll
        for (int j = 0; j < 64; ++j) {
            float4 b4 = Ks[swz4(j, tx)];
#pragma unroll
            for (int i = 0; i < 4; ++i) {
                float s = Sf[swz4(ty * 4 + i, j >> 2) * 4 + (j & 3)];
                fma4(o[i], s, b4);
            }
        }
        __syncthreads();
    }

#pragma unroll
    for (int i = 0; i < 4; ++i) {
        float* dst = O + ((size_t)bh * T_SEQ + rb * 64 + ty * 4 + i) * DH + tx * 4;
        *(float4*)dst = o[i];
    }
}

// ---------------------------------------------------------------------------
// Stage 4: out = mesa_out.reshape(B,T,d*H) @ Wo  (row permutation of Wo).
// ---------------------------------------------------------------------------
__global__ __launch_bounds__(256) void out_gemm(
    const float* __restrict__ A,
    const float* __restrict__ Wo, float* __restrict__ out) {
    int bm = blockIdx.x, bn = blockIdx.y;
    int tid = threadIdx.x;
    int tx = tid & 15, ty = tid >> 4;

    __shared__ float As[16 * 64];
    __shared__ float4 Bs[16 * 16];

    float4 acc[4];
    acc[0] = acc[1] = acc[2] = acc[3] = make_float4(0.f, 0.f, 0.f, 0.f);

    int ar = tid >> 2, ak4 = tid & 3;
    int m_ld = bm * 64 + ar;
    int b_ld = m_ld >> 10, t_ld = m_ld & 1023;
    int bkr = tid >> 4, bn4 = tid & 15;

    for (int bk = 0; bk < 32; ++bk) {
        int kkA = bk * 16 + ak4 * 4;
        int hA = kkA >> 6, ddA = kkA & 63;
        float4 a = *(const float4*)(A + ((size_t)(b_ld * NH + hA) * T_SEQ + t_ld) * DH + ddA);
        int kkB = bk * 16 + bkr;
        int hB = kkB >> 6, ddB = kkB & 63;
        float4 b = *(const float4*)(Wo + (size_t)(ddB * NH + hB) * EMB + bn * 64 + bn4 * 4);
        __syncthreads();
        As[(ak4 * 4 + 0) * 64 + ar] = a.x;
        As[(ak4 * 4 + 1) * 64 + ar] = a.y;
        As[(ak4 * 4 + 2) * 64 + ar] = a.z;
        As[(ak4 * 4 + 3) * 64 + ar] = a.w;
        Bs[bkr * 16 + bn4] = b;
        __syncthreads();
#pragma unroll
        for (int kk = 0; kk < 16; ++kk) {
            float4 a4 = ((const float4*)As)[kk * 16 + ty];
            float4 b4 = Bs[kk * 16 + tx];
            fma4(acc[0], a4.x, b4);
            fma4(acc[1], a4.y, b4);
            fma4(acc[2], a4.z, b4);
            fma4(acc[3], a4.w, b4);
        }
    }

#pragma unroll
    for (int i = 0; i < 4; ++i) {
        float* dst = out + (size_t)(bm * 64 + ty * 4 + i) * EMB + bn * 64 + tx * 4;
        *(float4*)dst = acc[i];
    }
}

extern "C" void kernel_launch(void* const* d_in, const int* in_sizes, int n_in,
                              void* d_out, int out_size, void* d_ws, size_t ws_size,
                              hipStream_t stream) {
    const float* x = (const float*)d_in[0];
    const float* Wq = (const float*)d_in[1];
    const float* Wk = (const float*)d_in[2];
    const float* Wv = (const float*)d_in[3];
    const float* Wo = (const float*)d_in[4];
    const float* lambdas = (const float*)d_in[5];
    float* out = (float*)d_out;

    float* ws = (float*)d_ws;
    const size_t SZ = (size_t)NB * NH * T_SEQ * DH;  // 1048576 floats
    float* q = ws;
    float* k = ws + SZ;
    float* v = ws + 2 * SZ;
    float* preds = ws + 3 * SZ;
    float* ao = ws + 4 * SZ;
    float* g = ws + 5 * SZ;  // NCHAIN*NCHUNK*4096 = 1048576 floats

    proj_gemm<<<dim3(32, 8, 3), 256, 0, stream>>>(x, Wq, Wk, Wv, q, k, v);
    gram_kernel<<<dim3(NCHAIN, NCHUNK), 256, 0, stream>>>(v, g);
    prefix_kernel<<<dim3(256), 256, 0, stream>>>(g);
    sweep_inv<<<dim3(NCHAIN * NCHUNK), 64, 0, stream>>>(g, lambdas);
    chunk_scan<<<dim3(NCHAIN * NCHUNK), 64, 0, stream>>>(v, q, g, preds);
    attn_kernel<<<dim3(16, 16), 256, 0, stream>>>(preds, v, k, ao);
    out_gemm<<<dim3(32, 8), 256, 0, stream>>>(ao, Wo, out);
}

// Round 3
// 355.246 us; speedup vs baseline: 4.0106x; 1.2427x over previous
//
#include <hip/hip_runtime.h>

#define T_SEQ 1024
#define DH 64
#define NH 8
#define NB 2
#define EMB 512
#define CS 32       // tokens per chunk
#define NCH 32      // chunks per chain
#define NCHAIN 16   // B*H

__device__ __forceinline__ int swz4(int r, int c4) {
    return r * 16 + ((c4 ^ (r >> 2)) & 15);
}

__device__ __forceinline__ void fma4(float4& o, float s, const float4& b) {
    o.x += s * b.x; o.y += s * b.y; o.z += s * b.z; o.w += s * b.w;
}

// ---------------------------------------------------------------------------
// Stage 1: q/k/v = x @ W{q,k,v}, written as [B,H,T,d] per-head layout.
// ---------------------------------------------------------------------------
__global__ __launch_bounds__(256) void proj_gemm(
    const float* __restrict__ x, const float* __restrict__ Wq,
    const float* __restrict__ Wk, const float* __restrict__ Wv,
    float* __restrict__ q, float* __restrict__ k, float* __restrict__ v) {
    const float* W = (blockIdx.z == 0) ? Wq : (blockIdx.z == 1) ? Wk : Wv;
    float* out = (blockIdx.z == 0) ? q : (blockIdx.z == 1) ? k : v;
    int bm = blockIdx.x, bn = blockIdx.y;
    int tid = threadIdx.x;
    int tx = tid & 15, ty = tid >> 4;

    __shared__ float As[16 * 64];   // [k][m]
    __shared__ float4 Bs[16 * 16];  // [k][n4]

    float4 acc[4];
    acc[0] = acc[1] = acc[2] = acc[3] = make_float4(0.f, 0.f, 0.f, 0.f);

    int ar = tid >> 2, ak4 = tid & 3;
    int bkr = tid >> 4, bn4 = tid & 15;
    const float* Aptr = x + (size_t)(bm * 64 + ar) * EMB + ak4 * 4;
    const float* Bptr = W + (size_t)bkr * EMB + bn * 64 + bn4 * 4;

    for (int k0 = 0; k0 < EMB; k0 += 16) {
        float4 a = *(const float4*)(Aptr + k0);
        float4 b = *(const float4*)(Bptr + (size_t)k0 * EMB);
        __syncthreads();
        As[(ak4 * 4 + 0) * 64 + ar] = a.x;
        As[(ak4 * 4 + 1) * 64 + ar] = a.y;
        As[(ak4 * 4 + 2) * 64 + ar] = a.z;
        As[(ak4 * 4 + 3) * 64 + ar] = a.w;
        Bs[bkr * 16 + bn4] = b;
        __syncthreads();
#pragma unroll
        for (int kk = 0; kk < 16; ++kk) {
            float4 a4 = ((const float4*)As)[kk * 16 + ty];
            float4 b4 = Bs[kk * 16 + tx];
            fma4(acc[0], a4.x, b4);
            fma4(acc[1], a4.y, b4);
            fma4(acc[2], a4.z, b4);
            fma4(acc[3], a4.w, b4);
        }
    }

#pragma unroll
    for (int i = 0; i < 4; ++i) {
        int mm = bm * 64 + ty * 4 + i;
        int bb = mm >> 10, t = mm & 1023;
        float* dst = out + ((size_t)(bb * NH + bn) * T_SEQ + t) * DH + tx * 4;
        *(float4*)dst = acc[i];
    }
}

// ---------------------------------------------------------------------------
// Stage 2a: per-chunk Gram matrices G = X_chunk^T X_chunk (64x64, CS tokens)
// ---------------------------------------------------------------------------
__global__ __launch_bounds__(256) void gram_kernel(
    const float* __restrict__ v, float* __restrict__ g) {
    int chain = blockIdx.x, chunk = blockIdx.y;
    const float* X = v + ((size_t)chain * T_SEQ + chunk * CS) * DH;
    __shared__ float Xs[CS * 64];
    int tid = threadIdx.x;
#pragma unroll
    for (int i = 0; i < (CS * 16) / 256; ++i)
        ((float4*)Xs)[i * 256 + tid] = ((const float4*)X)[i * 256 + tid];
    __syncthreads();

    int tx = tid & 15, ty = tid >> 4;
    float acc[4][4];
#pragma unroll
    for (int i = 0; i < 4; ++i)
#pragma unroll
        for (int j = 0; j < 4; ++j) acc[i][j] = 0.f;

#pragma unroll 4
    for (int t = 0; t < CS; ++t) {
        float a_[4], b_[4];
#pragma unroll
        for (int i = 0; i < 4; ++i) a_[i] = Xs[t * 64 + ty * 4 + i];
#pragma unroll
        for (int j = 0; j < 4; ++j) b_[j] = Xs[t * 64 + tx * 4 + j];
#pragma unroll
        for (int i = 0; i < 4; ++i)
#pragma unroll
            for (int j = 0; j < 4; ++j) acc[i][j] += a_[i] * b_[j];
    }

    float* gp = g + ((size_t)chain * NCH + chunk) * 4096;
#pragma unroll
    for (int i = 0; i < 4; ++i)
        *(float4*)(gp + (ty * 4 + i) * 64 + tx * 4) =
            make_float4(acc[i][0], acc[i][1], acc[i][2], acc[i][3]);
}

// ---------------------------------------------------------------------------
// Stage 2b: in-place EXCLUSIVE prefix sum of Gram matrices over chunks
// ---------------------------------------------------------------------------
__global__ __launch_bounds__(256) void prefix_kernel(float* __restrict__ g) {
    int gid = blockIdx.x * 256 + threadIdx.x;   // 16 chains * 4096 elems
    int chain = gid >> 12, elem = gid & 4095;
    float* p = g + (size_t)chain * NCH * 4096 + elem;
    float run = 0.f;
#pragma unroll
    for (int c = 0; c < NCH; ++c) {
        float val = p[(size_t)c * 4096];
        p[(size_t)c * 4096] = run;
        run += val;
    }
}

// ---------------------------------------------------------------------------
// Stage 2c+2d fused: GJ-invert (lam*I + S) in LDS (symmetric sweep), then
// Sherman-Morrison scan over the chunk's CS tokens. One wave per (chain,chunk).
// Matrix lives in LDS with float4-slot XOR swizzle: row l, col-block cb is at
// slot l*16 + (cb ^ (l&15)). Symmetry => pivot column == pivot row, so no
// runtime register indexing exists anywhere (no spill possible).
// ---------------------------------------------------------------------------
__global__ __launch_bounds__(64) void invscan(
    const float* __restrict__ g, const float* __restrict__ v,
    const float* __restrict__ q, const float* __restrict__ lambdas,
    float* __restrict__ preds) {
    int blk = blockIdx.x;
    int chain = blk >> 5, chunk = blk & 31;
    int lane = threadIdx.x;
    float lam = lambdas[chain & (NH - 1)];

    __shared__ float Mf[64 * 64];
    __shared__ float Xs[CS * 64];
    __shared__ float Qs[CS * 64];
    __shared__ float hxs[64];
    float4* M4 = (float4*)Mf;
    const int lsw = lane & 15;

    // Load exclusive-prefix Gram, store swizzled; M = S (lam added below).
    const float4* gp = (const float4*)(g + (size_t)blk * 4096);
#pragma unroll
    for (int cb = 0; cb < 16; ++cb)
        M4[lane * 16 + (cb ^ lsw)] = gp[lane * 16 + cb];

    const float* vb = v + ((size_t)chain * T_SEQ + chunk * CS) * DH;
    const float* qb = q + ((size_t)chain * T_SEQ + chunk * CS) * DH;
#pragma unroll
    for (int i = 0; i < (CS * 16) / 64; ++i) {
        ((float4*)Xs)[i * 64 + lane] = ((const float4*)vb)[i * 64 + lane];
        ((float4*)Qs)[i * 64 + lane] = ((const float4*)qb)[i * 64 + lane];
    }
    __syncthreads();
    // diagonal += lam (own row's diagonal element)
    Mf[lane * 64 + (((lane >> 2) ^ lsw) << 2) + (lane & 3)] += lam;
    __syncthreads();

    // ---- GJ sweep: after all 64 pivots, M = -(lam*I + S)^{-1} ----
    for (int p = 0; p < 64; ++p) {
        int psw = p & 15;
        int pcb = p >> 2, pel = p & 3;
        float gcv = Mf[lane * 64 + ((pcb ^ lsw) << 2) + pel];   // M[lane][p]
        float piv = Mf[p * 64 + ((pcb ^ psw) << 2) + pel];      // M[p][p]
        float ipiv = 1.f / piv;
        bool isp = (lane == p);
        float beta = gcv * ipiv;
        float c1 = isp ? 0.f : 1.f;
        float c2 = isp ? ipiv : -beta;
#pragma unroll
        for (int cb = 0; cb < 16; ++cb) {
            int so = lane * 16 + (cb ^ lsw);
            float4 own = M4[so];
            float4 prow = M4[p * 16 + (cb ^ psw)];  // uniform -> broadcast
            own.x = c1 * own.x + c2 * prow.x;
            own.y = c1 * own.y + c2 * prow.y;
            own.z = c1 * own.z + c2 * prow.z;
            own.w = c1 * own.w + c2 * prow.w;
            M4[so] = own;
        }
        // fix column-p element of own row
        Mf[lane * 64 + ((pcb ^ lsw) << 2) + pel] = isp ? -ipiv : beta;
    }
    __syncthreads();

    // ---- Sherman-Morrison scan over CS tokens (H = -M, kept in LDS) ----
    float* pb = preds + ((size_t)chain * T_SEQ + chunk * CS) * DH;
    for (int t = 0; t < CS; ++t) {
        float4 hxa = make_float4(0.f, 0.f, 0.f, 0.f);
        float4 hqa = make_float4(0.f, 0.f, 0.f, 0.f);
#pragma unroll
        for (int cb = 0; cb < 16; ++cb) {
            float4 m = M4[lane * 16 + (cb ^ lsw)];
            float4 x4 = ((const float4*)Xs)[t * 16 + cb];  // uniform
            float4 q4 = ((const float4*)Qs)[t * 16 + cb];  // uniform
            hxa.x += m.x * x4.x; hxa.y += m.y * x4.y;
            hxa.z += m.z * x4.z; hxa.w += m.w * x4.w;
            hqa.x += m.x * q4.x; hqa.y += m.y * q4.y;
            hqa.z += m.z * q4.z; hqa.w += m.w * q4.w;
        }
        float Hx = -((hxa.x + hxa.y) + (hxa.z + hxa.w));
        float Hq = -((hqa.x + hqa.y) + (hqa.z + hqa.w));

        float xv = Xs[t * 64 + lane];
        float qv = Qs[t * 64 + lane];
        float p1 = xv * Hx;
        float p2 = qv * Hx;
#pragma unroll
        for (int off = 32; off; off >>= 1) {
            p1 += __shfl_xor(p1, off);
            p2 += __shfl_xor(p2, off);
        }
        float idn = 1.f / (1.f + p1);
        pb[(size_t)t * DH + lane] = Hq - Hx * (p2 * idn);

        hxs[lane] = Hx;
        __syncthreads();
        float coef = Hx * idn;   // H -= coef*Hx[j]  =>  M += coef*Hx[j]
#pragma unroll
        for (int cb = 0; cb < 16; ++cb) {
            int so = lane * 16 + (cb ^ lsw);
            float4 m = M4[so];
            float4 h4 = ((const float4*)hxs)[cb];  // uniform
            m.x += coef * h4.x; m.y += coef * h4.y;
            m.z += coef * h4.z; m.w += coef * h4.w;
            M4[so] = m;
        }
        __syncthreads();
    }
}

// ---------------------------------------------------------------------------
// Stage 3: O = tril(P @ V^T) @ K per (b,h), 64-row blocks, causal col blocks.
// ---------------------------------------------------------------------------
__global__ __launch_bounds__(256) void attn_kernel(
    const float* __restrict__ P, const float* __restrict__ V,
    const float* __restrict__ Kv, float* __restrict__ O) {
    int rb = blockIdx.x, bh = blockIdx.y;
    int tid = threadIdx.x, tx = tid & 15, ty = tid >> 4;

    __shared__ float4 Ps[64 * 16];
    __shared__ float4 Vs[64 * 16];
    __shared__ float4 Ks[64 * 16];

    int lr = tid >> 2, lc = tid & 3;
    const float4* Pb = (const float4*)(P + ((size_t)bh * T_SEQ + rb * 64) * DH);
#pragma unroll
    for (int i = 0; i < 4; ++i)
        Ps[swz4(lr, lc + i * 4)] = Pb[lr * 16 + lc + i * 4];

    float4 o[4];
    o[0] = o[1] = o[2] = o[3] = make_float4(0.f, 0.f, 0.f, 0.f);
    __syncthreads();

    for (int cb = 0; cb <= rb; ++cb) {
        const float4* Vb = (const float4*)(V + ((size_t)bh * T_SEQ + cb * 64) * DH);
        const float4* Kb = (const float4*)(Kv + ((size_t)bh * T_SEQ + cb * 64) * DH);
#pragma unroll
        for (int i = 0; i < 4; ++i) {
            Vs[swz4(lr, lc + i * 4)] = Vb[lr * 16 + lc + i * 4];
            Ks[swz4(lr, lc + i * 4)] = Kb[lr * 16 + lc + i * 4];
        }
        __syncthreads();

        float4 sa[4][4];
#pragma unroll
        for (int i = 0; i < 4; ++i)
#pragma unroll
            for (int j = 0; j < 4; ++j) sa[i][j] = make_float4(0.f, 0.f, 0.f, 0.f);
#pragma unroll
        for (int d4 = 0; d4 < 16; ++d4) {
            float4 a[4], b[4];
#pragma unroll
            for (int i = 0; i < 4; ++i) a[i] = Ps[swz4(ty * 4 + i, d4)];
#pragma unroll
            for (int j = 0; j < 4; ++j) b[j] = Vs[swz4(tx * 4 + j, d4)];
#pragma unroll
            for (int i = 0; i < 4; ++i)
#pragma unroll
                for (int j = 0; j < 4; ++j) {
                    sa[i][j].x += a[i].x * b[j].x;
                    sa[i][j].y += a[i].y * b[j].y;
                    sa[i][j].z += a[i].z * b[j].z;
                    sa[i][j].w += a[i].w * b[j].w;
                }
        }
        __syncthreads();

        bool diag = (cb == rb);
#pragma unroll
        for (int i = 0; i < 4; ++i) {
            int m = ty * 4 + i;
            float sv[4];
#pragma unroll
            for (int j = 0; j < 4; ++j) {
                float s = sa[i][j].x + sa[i][j].y + sa[i][j].z + sa[i][j].w;
                if (diag && (tx * 4 + j) > m) s = 0.f;
                sv[j] = s;
            }
            Vs[swz4(m, tx)] = make_float4(sv[0], sv[1], sv[2], sv[3]);
        }
        __syncthreads();

        const float* Sf = (const float*)Vs;
#pragma unroll
        for (int j = 0; j < 64; ++j) {
            float4 b4 = Ks[swz4(j, tx)];
#pragma unroll
            for (int i = 0; i < 4; ++i) {
                float s = Sf[swz4(ty * 4 + i, j >> 2) * 4 + (j & 3)];
                fma4(o[i], s, b4);
            }
        }
        __syncthreads();
    }

#pragma unroll
    for (int i = 0; i < 4; ++i) {
        float* dst = O + ((size_t)bh * T_SEQ + rb * 64 + ty * 4 + i) * DH + tx * 4;
        *(float4*)dst = o[i];
    }
}

// ---------------------------------------------------------------------------
// Stage 4: out = mesa_out.reshape(B,T,d*H) @ Wo  (row permutation of Wo).
// ---------------------------------------------------------------------------
__global__ __launch_bounds__(256) void out_gemm(
    const float* __restrict__ A,
    const float* __restrict__ Wo, float* __restrict__ out) {
    int bm = blockIdx.x, bn = blockIdx.y;
    int tid = threadIdx.x;
    int tx = tid & 15, ty = tid >> 4;

    __shared__ float As[16 * 64];
    __shared__ float4 Bs[16 * 16];

    float4 acc[4];
    acc[0] = acc[1] = acc[2] = acc[3] = make_float4(0.f, 0.f, 0.f, 0.f);

    int ar = tid >> 2, ak4 = tid & 3;
    int m_ld = bm * 64 + ar;
    int b_ld = m_ld >> 10, t_ld = m_ld & 1023;
    int bkr = tid >> 4, bn4 = tid & 15;

    for (int bk = 0; bk < 32; ++bk) {
        int kkA = bk * 16 + ak4 * 4;
        int hA = kkA >> 6, ddA = kkA & 63;
        float4 a = *(const float4*)(A + ((size_t)(b_ld * NH + hA) * T_SEQ + t_ld) * DH + ddA);
        int kkB = bk * 16 + bkr;
        int hB = kkB >> 6, ddB = kkB & 63;
        float4 b = *(const float4*)(Wo + (size_t)(ddB * NH + hB) * EMB + bn * 64 + bn4 * 4);
        __syncthreads();
        As[(ak4 * 4 + 0) * 64 + ar] = a.x;
        As[(ak4 * 4 + 1) * 64 + ar] = a.y;
        As[(ak4 * 4 + 2) * 64 + ar] = a.z;
        As[(ak4 * 4 + 3) * 64 + ar] = a.w;
        Bs[bkr * 16 + bn4] = b;
        __syncthreads();
#pragma unroll
        for (int kk = 0; kk < 16; ++kk) {
            float4 a4 = ((const float4*)As)[kk * 16 + ty];
            float4 b4 = Bs[kk * 16 + tx];
            fma4(acc[0], a4.x, b4);
            fma4(acc[1], a4.y, b4);
            fma4(acc[2], a4.z, b4);
            fma4(acc[3], a4.w, b4);
        }
    }

#pragma unroll
    for (int i = 0; i < 4; ++i) {
        float* dst = out + (size_t)(bm * 64 + ty * 4 + i) * EMB + bn * 64 + tx * 4;
        *(float4*)dst = acc[i];
    }
}

extern "C" void kernel_launch(void* const* d_in, const int* in_sizes, int n_in,
                              void* d_out, int out_size, void* d_ws, size_t ws_size,
                              hipStream_t stream) {
    const float* x = (const float*)d_in[0];
    const float* Wq = (const float*)d_in[1];
    const float* Wk = (const float*)d_in[2];
    const float* Wv = (const float*)d_in[3];
    const float* Wo = (const float*)d_in[4];
    const float* lambdas = (const float*)d_in[5];
    float* out = (float*)d_out;

    float* ws = (float*)d_ws;
    const size_t SZ = (size_t)NB * NH * T_SEQ * DH;  // 1048576 floats (4 MB)
    float* q = ws;
    float* k = ws + SZ;
    float* v = ws + 2 * SZ;
    float* preds = ws + 3 * SZ;
    float* g = ws + 4 * SZ;   // NCHAIN*NCH*4096 = 2M floats (8 MB)
    float* ao = g;            // alias: attn output reuses g (g dead by then)

    proj_gemm<<<dim3(32, 8, 3), 256, 0, stream>>>(x, Wq, Wk, Wv, q, k, v);
    gram_kernel<<<dim3(NCHAIN, NCH), 256, 0, stream>>>(v, g);
    prefix_kernel<<<dim3(256), 256, 0, stream>>>(g);
    invscan<<<dim3(NCHAIN * NCH), 64, 0, stream>>>(g, v, q, lambdas, preds);
    attn_kernel<<<dim3(16, 16), 256, 0, stream>>>(preds, v, k, ao);
    out_gemm<<<dim3(32, 8), 256, 0, stream>>>(ao, Wo, out);
}

// Round 4
// 283.510 us; speedup vs baseline: 5.0254x; 1.2530x over previous
//
#include <hip/hip_runtime.h>

#define T_SEQ 1024
#define DH 64
#define NH 8
#define NB 2
#define EMB 512
#define CS 32       // tokens per chunk
#define NCH 32      // chunks per chain
#define NCHAIN 16   // B*H

__device__ __forceinline__ int swz4(int r, int c4) {
    return r * 16 + ((c4 ^ (r >> 2)) & 15);
}

__device__ __forceinline__ void fma4(float4& o, float s, const float4& b) {
    o.x += s * b.x; o.y += s * b.y; o.z += s * b.z; o.w += s * b.w;
}

// ---------------------------------------------------------------------------
// Stage 1: q/k/v = x @ W{q,k,v}, written as [B,H,T,d] per-head layout.
// ---------------------------------------------------------------------------
__global__ __launch_bounds__(256) void proj_gemm(
    const float* __restrict__ x, const float* __restrict__ Wq,
    const float* __restrict__ Wk, const float* __restrict__ Wv,
    float* __restrict__ q, float* __restrict__ k, float* __restrict__ v) {
    const float* W = (blockIdx.z == 0) ? Wq : (blockIdx.z == 1) ? Wk : Wv;
    float* out = (blockIdx.z == 0) ? q : (blockIdx.z == 1) ? k : v;
    int bm = blockIdx.x, bn = blockIdx.y;
    int tid = threadIdx.x;
    int tx = tid & 15, ty = tid >> 4;

    __shared__ float As[16 * 64];   // [k][m]
    __shared__ float4 Bs[16 * 16];  // [k][n4]

    float4 acc[4];
    acc[0] = acc[1] = acc[2] = acc[3] = make_float4(0.f, 0.f, 0.f, 0.f);

    int ar = tid >> 2, ak4 = tid & 3;
    int bkr = tid >> 4, bn4 = tid & 15;
    const float* Aptr = x + (size_t)(bm * 64 + ar) * EMB + ak4 * 4;
    const float* Bptr = W + (size_t)bkr * EMB + bn * 64 + bn4 * 4;

    for (int k0 = 0; k0 < EMB; k0 += 16) {
        float4 a = *(const float4*)(Aptr + k0);
        float4 b = *(const float4*)(Bptr + (size_t)k0 * EMB);
        __syncthreads();
        As[(ak4 * 4 + 0) * 64 + ar] = a.x;
        As[(ak4 * 4 + 1) * 64 + ar] = a.y;
        As[(ak4 * 4 + 2) * 64 + ar] = a.z;
        As[(ak4 * 4 + 3) * 64 + ar] = a.w;
        Bs[bkr * 16 + bn4] = b;
        __syncthreads();
#pragma unroll
        for (int kk = 0; kk < 16; ++kk) {
            float4 a4 = ((const float4*)As)[kk * 16 + ty];
            float4 b4 = Bs[kk * 16 + tx];
            fma4(acc[0], a4.x, b4);
            fma4(acc[1], a4.y, b4);
            fma4(acc[2], a4.z, b4);
            fma4(acc[3], a4.w, b4);
        }
    }

#pragma unroll
    for (int i = 0; i < 4; ++i) {
        int mm = bm * 64 + ty * 4 + i;
        int bb = mm >> 10, t = mm & 1023;
        float* dst = out + ((size_t)(bb * NH + bn) * T_SEQ + t) * DH + tx * 4;
        *(float4*)dst = acc[i];
    }
}

// ---------------------------------------------------------------------------
// Stage 2a: per-chunk Gram matrices G = X_chunk^T X_chunk (64x64, CS tokens)
// ---------------------------------------------------------------------------
__global__ __launch_bounds__(256) void gram_kernel(
    const float* __restrict__ v, float* __restrict__ g) {
    int chain = blockIdx.x, chunk = blockIdx.y;
    const float* X = v + ((size_t)chain * T_SEQ + chunk * CS) * DH;
    __shared__ float Xs[CS * 64];
    int tid = threadIdx.x;
#pragma unroll
    for (int i = 0; i < (CS * 16) / 256; ++i)
        ((float4*)Xs)[i * 256 + tid] = ((const float4*)X)[i * 256 + tid];
    __syncthreads();

    int tx = tid & 15, ty = tid >> 4;
    float acc[4][4];
#pragma unroll
    for (int i = 0; i < 4; ++i)
#pragma unroll
        for (int j = 0; j < 4; ++j) acc[i][j] = 0.f;

#pragma unroll 4
    for (int t = 0; t < CS; ++t) {
        float a_[4], b_[4];
#pragma unroll
        for (int i = 0; i < 4; ++i) a_[i] = Xs[t * 64 + ty * 4 + i];
#pragma unroll
        for (int j = 0; j < 4; ++j) b_[j] = Xs[t * 64 + tx * 4 + j];
#pragma unroll
        for (int i = 0; i < 4; ++i)
#pragma unroll
            for (int j = 0; j < 4; ++j) acc[i][j] += a_[i] * b_[j];
    }

    float* gp = g + ((size_t)chain * NCH + chunk) * 4096;
#pragma unroll
    for (int i = 0; i < 4; ++i)
        *(float4*)(gp + (ty * 4 + i) * 64 + tx * 4) =
            make_float4(acc[i][0], acc[i][1], acc[i][2], acc[i][3]);
}

// ---------------------------------------------------------------------------
// Stage 2b: in-place EXCLUSIVE prefix sum of Gram matrices over chunks
// ---------------------------------------------------------------------------
__global__ __launch_bounds__(256) void prefix_kernel(float* __restrict__ g) {
    int gid = blockIdx.x * 256 + threadIdx.x;   // 16 chains * 4096 elems
    int chain = gid >> 12, elem = gid & 4095;
    float* p = g + (size_t)chain * NCH * 4096 + elem;
    float run = 0.f;
#pragma unroll
    for (int c = 0; c < NCH; ++c) {
        float val = p[(size_t)c * 4096];
        p[(size_t)c * 4096] = run;
        run += val;
    }
}

// ---------------------------------------------------------------------------
// Stage 2c+2d fused: GJ-invert (lam*I + S) in LDS, then Sherman-Morrison scan.
// 256 threads per matrix: thread = (row = tid>>2, col-chunk = tid&3).
// Each thread owns 4 float4 slots (16 cols) of its row. Read phase and write
// phase are separated by barriers so LDS reads batch (no RAW serialization).
// Swizzle: row r, float4 slot cb lives at M4[r*16 + (cb ^ (r&15))].
// ---------------------------------------------------------------------------
__global__ __launch_bounds__(256) void invscan(
    const float* __restrict__ g, const float* __restrict__ v,
    const float* __restrict__ q, const float* __restrict__ lambdas,
    float* __restrict__ preds) {
    int blk = blockIdx.x;
    int chain = blk >> 5, chunk = blk & 31;
    int tid = threadIdx.x;
    int row = tid >> 2;       // 0..63
    int ch = tid & 3;         // chunk of 4 float4 slots
    int rsw = row & 15;
    int wav = tid >> 6;       // wave id 0..3
    float lam = lambdas[chain & (NH - 1)];

    __shared__ float Mf[64 * 64];
    __shared__ float Xs[CS * 64];
    __shared__ float Qs[CS * 64];
    __shared__ float hxs[64];
    __shared__ float red1[4], red2[4];
    float4* M4 = (float4*)Mf;

    // ---- load prefix-Gram into swizzled LDS (coalesced) ----
    const float4* gp = (const float4*)(g + (size_t)blk * 4096);
#pragma unroll
    for (int i = 0; i < 4; ++i) {
        int cb = ch * 4 + i;
        M4[row * 16 + (cb ^ rsw)] = gp[row * 16 + cb];
    }
    const float4* vb = (const float4*)(v + ((size_t)chain * T_SEQ + chunk * CS) * DH);
    const float4* qb = (const float4*)(q + ((size_t)chain * T_SEQ + chunk * CS) * DH);
    ((float4*)Xs)[tid] = vb[tid];
    ((float4*)Xs)[256 + tid] = vb[256 + tid];
    ((float4*)Qs)[tid] = qb[tid];
    ((float4*)Qs)[256 + tid] = qb[256 + tid];
    __syncthreads();
    // diagonal += lam: row's diag col = row -> slot row>>2 (owner chunk row>>4)
    if (ch == (row >> 4))
        Mf[row * 64 + (((row >> 2) ^ rsw) << 2) + (row & 3)] += lam;
    __syncthreads();

    // ---- GJ sweep: after 64 pivots, M = -(lam*I + S)^{-1} ----
    for (int p = 0; p < 64; ++p) {
        int psw = p & 15, pcb = p >> 2, pel = p & 3;
        // read phase (batched)
        float gcv = Mf[row * 64 + ((pcb ^ rsw) << 2) + pel];   // M[row][p]
        float piv = Mf[p * 64 + ((pcb ^ psw) << 2) + pel];     // M[p][p]
        float4 own[4], prow[4];
#pragma unroll
        for (int i = 0; i < 4; ++i) {
            int cb = ch * 4 + i;
            own[i] = M4[row * 16 + (cb ^ rsw)];
            prow[i] = M4[p * 16 + (cb ^ psw)];   // uniform -> broadcast
        }
        __syncthreads();
        float ipiv = 1.f / piv;
        bool isp = (row == p);
        float beta = gcv * ipiv;
        float c1 = isp ? 0.f : 1.f;
        float c2 = isp ? ipiv : -beta;
#pragma unroll
        for (int i = 0; i < 4; ++i) {
            int cb = ch * 4 + i;
            float4 o = own[i], pr = prow[i];
            o.x = c1 * o.x + c2 * pr.x;
            o.y = c1 * o.y + c2 * pr.y;
            o.z = c1 * o.z + c2 * pr.z;
            o.w = c1 * o.w + c2 * pr.w;
            M4[row * 16 + (cb ^ rsw)] = o;
        }
        if (ch == (pcb >> 2))   // patch col-p of own row
            Mf[row * 64 + ((pcb ^ rsw) << 2) + pel] = isp ? -ipiv : beta;
        __syncthreads();
    }

    // ---- Sherman-Morrison scan over CS tokens (H = -M) ----
    float* pb = preds + ((size_t)chain * T_SEQ + chunk * CS) * DH;
    for (int t = 0; t < CS; ++t) {
        float4 mreg[4];
        float hx = 0.f, hq = 0.f;
#pragma unroll
        for (int i = 0; i < 4; ++i) {
            int cb = ch * 4 + i;
            float4 m = M4[row * 16 + (cb ^ rsw)];
            mreg[i] = m;
            float4 x4 = ((const float4*)Xs)[t * 16 + cb];  // uniform
            float4 q4 = ((const float4*)Qs)[t * 16 + cb];  // uniform
            hx += m.x * x4.x + m.y * x4.y + m.z * x4.z + m.w * x4.w;
            hq += m.x * q4.x + m.y * q4.y + m.z * q4.z + m.w * q4.w;
        }
        // quad reduce -> full row dot in all 4 quad lanes
        hx += __shfl_xor(hx, 1); hx += __shfl_xor(hx, 2);
        hq += __shfl_xor(hq, 1); hq += __shfl_xor(hq, 2);
        float Hx = -hx, Hq = -hq;

        float xr = Xs[t * 64 + row];
        float qr = Qs[t * 64 + row];
        float s1 = xr * Hx, s2 = qr * Hx;   // each row duplicated 4x in wave
#pragma unroll
        for (int off = 32; off; off >>= 1) {
            s1 += __shfl_xor(s1, off);
            s2 += __shfl_xor(s2, off);
        }
        if ((tid & 63) == 0) { red1[wav] = s1; red2[wav] = s2; }
        if ((tid & 3) == 0) hxs[row] = Hx;
        __syncthreads();
        float p1 = 0.25f * (red1[0] + red1[1] + red1[2] + red1[3]);
        float p2 = 0.25f * (red2[0] + red2[1] + red2[2] + red2[3]);
        float idn = 1.f / (1.f + p1);
        if ((tid & 3) == 0) pb[(size_t)t * DH + row] = Hq - Hx * (p2 * idn);

        float coef = Hx * idn;   // M += coef * Hx[col]
#pragma unroll
        for (int i = 0; i < 4; ++i) {
            int cb = ch * 4 + i;
            float4 m = mreg[i];
            float4 h4 = ((const float4*)hxs)[cb];  // uniform
            m.x += coef * h4.x; m.y += coef * h4.y;
            m.z += coef * h4.z; m.w += coef * h4.w;
            M4[row * 16 + (cb ^ rsw)] = m;
        }
        __syncthreads();
    }
}

// ---------------------------------------------------------------------------
// Stage 3: O = tril(P @ V^T) @ K per (b,h), 64-row blocks, causal col blocks.
// ---------------------------------------------------------------------------
__global__ __launch_bounds__(256) void attn_kernel(
    const float* __restrict__ P, const float* __restrict__ V,
    const float* __restrict__ Kv, float* __restrict__ O) {
    int rb = blockIdx.x, bh = blockIdx.y;
    int tid = threadIdx.x, tx = tid & 15, ty = tid >> 4;

    __shared__ float4 Ps[64 * 16];
    __shared__ float4 Vs[64 * 16];
    __shared__ float4 Ks[64 * 16];

    int lr = tid >> 2, lc = tid & 3;
    const float4* Pb = (const float4*)(P + ((size_t)bh * T_SEQ + rb * 64) * DH);
#pragma unroll
    for (int i = 0; i < 4; ++i)
        Ps[swz4(lr, lc + i * 4)] = Pb[lr * 16 + lc + i * 4];

    float4 o[4];
    o[0] = o[1] = o[2] = o[3] = make_float4(0.f, 0.f, 0.f, 0.f);
    __syncthreads();

    for (int cb = 0; cb <= rb; ++cb) {
        const float4* Vb = (const float4*)(V + ((size_t)bh * T_SEQ + cb * 64) * DH);
        const float4* Kb = (const float4*)(Kv + ((size_t)bh * T_SEQ + cb * 64) * DH);
#pragma unroll
        for (int i = 0; i < 4; ++i) {
            Vs[swz4(lr, lc + i * 4)] = Vb[lr * 16 + lc + i * 4];
            Ks[swz4(lr, lc + i * 4)] = Kb[lr * 16 + lc + i * 4];
        }
        __syncthreads();

        float4 sa[4][4];
#pragma unroll
        for (int i = 0; i < 4; ++i)
#pragma unroll
            for (int j = 0; j < 4; ++j) sa[i][j] = make_float4(0.f, 0.f, 0.f, 0.f);
#pragma unroll
        for (int d4 = 0; d4 < 16; ++d4) {
            float4 a[4], b[4];
#pragma unroll
            for (int i = 0; i < 4; ++i) a[i] = Ps[swz4(ty * 4 + i, d4)];
#pragma unroll
            for (int j = 0; j < 4; ++j) b[j] = Vs[swz4(tx * 4 + j, d4)];
#pragma unroll
            for (int i = 0; i < 4; ++i)
#pragma unroll
                for (int j = 0; j < 4; ++j) {
                    sa[i][j].x += a[i].x * b[j].x;
                    sa[i][j].y += a[i].y * b[j].y;
                    sa[i][j].z += a[i].z * b[j].z;
                    sa[i][j].w += a[i].w * b[j].w;
                }
        }
        __syncthreads();

        bool diag = (cb == rb);
#pragma unroll
        for (int i = 0; i < 4; ++i) {
            int m = ty * 4 + i;
            float sv[4];
#pragma unroll
            for (int j = 0; j < 4; ++j) {
                float s = sa[i][j].x + sa[i][j].y + sa[i][j].z + sa[i][j].w;
                if (diag && (tx * 4 + j) > m) s = 0.f;
                sv[j] = s;
            }
            Vs[swz4(m, tx)] = make_float4(sv[0], sv[1], sv[2], sv[3]);
        }
        __syncthreads();

        const float* Sf = (const float*)Vs;
#pragma unroll
        for (int j = 0; j < 64; ++j) {
            float4 b4 = Ks[swz4(j, tx)];
#pragma unroll
            for (int i = 0; i < 4; ++i) {
                float s = Sf[swz4(ty * 4 + i, j >> 2) * 4 + (j & 3)];
                fma4(o[i], s, b4);
            }
        }
        __syncthreads();
    }

#pragma unroll
    for (int i = 0; i < 4; ++i) {
        float* dst = O + ((size_t)bh * T_SEQ + rb * 64 + ty * 4 + i) * DH + tx * 4;
        *(float4*)dst = o[i];
    }
}

// ---------------------------------------------------------------------------
// Stage 4: out = mesa_out.reshape(B,T,d*H) @ Wo  (row permutation of Wo).
// ---------------------------------------------------------------------------
__global__ __launch_bounds__(256) void out_gemm(
    const float* __restrict__ A,
    const float* __restrict__ Wo, float* __restrict__ out) {
    int bm = blockIdx.x, bn = blockIdx.y;
    int tid = threadIdx.x;
    int tx = tid & 15, ty = tid >> 4;

    __shared__ float As[16 * 64];
    __shared__ float4 Bs[16 * 16];

    float4 acc[4];
    acc[0] = acc[1] = acc[2] = acc[3] = make_float4(0.f, 0.f, 0.f, 0.f);

    int ar = tid >> 2, ak4 = tid & 3;
    int m_ld = bm * 64 + ar;
    int b_ld = m_ld >> 10, t_ld = m_ld & 1023;
    int bkr = tid >> 4, bn4 = tid & 15;

    for (int bk = 0; bk < 32; ++bk) {
        int kkA = bk * 16 + ak4 * 4;
        int hA = kkA >> 6, ddA = kkA & 63;
        float4 a = *(const float4*)(A + ((size_t)(b_ld * NH + hA) * T_SEQ + t_ld) * DH + ddA);
        int kkB = bk * 16 + bkr;
        int hB = kkB >> 6, ddB = kkB & 63;
        float4 b = *(const float4*)(Wo + (size_t)(ddB * NH + hB) * EMB + bn * 64 + bn4 * 4);
        __syncthreads();
        As[(ak4 * 4 + 0) * 64 + ar] = a.x;
        As[(ak4 * 4 + 1) * 64 + ar] = a.y;
        As[(ak4 * 4 + 2) * 64 + ar] = a.z;
        As[(ak4 * 4 + 3) * 64 + ar] = a.w;
        Bs[bkr * 16 + bn4] = b;
        __syncthreads();
#pragma unroll
        for (int kk = 0; kk < 16; ++kk) {
            float4 a4 = ((const float4*)As)[kk * 16 + ty];
            float4 b4 = Bs[kk * 16 + tx];
            fma4(acc[0], a4.x, b4);
            fma4(acc[1], a4.y, b4);
            fma4(acc[2], a4.z, b4);
            fma4(acc[3], a4.w, b4);
        }
    }

#pragma unroll
    for (int i = 0; i < 4; ++i) {
        float* dst = out + (size_t)(bm * 64 + ty * 4 + i) * EMB + bn * 64 + tx * 4;
        *(float4*)dst = acc[i];
    }
}

extern "C" void kernel_launch(void* const* d_in, const int* in_sizes, int n_in,
                              void* d_out, int out_size, void* d_ws, size_t ws_size,
                              hipStream_t stream) {
    const float* x = (const float*)d_in[0];
    const float* Wq = (const float*)d_in[1];
    const float* Wk = (const float*)d_in[2];
    const float* Wv = (const float*)d_in[3];
    const float* Wo = (const float*)d_in[4];
    const float* lambdas = (const float*)d_in[5];
    float* out = (float*)d_out;

    float* ws = (float*)d_ws;
    const size_t SZ = (size_t)NB * NH * T_SEQ * DH;  // 1048576 floats (4 MB)
    float* q = ws;
    float* k = ws + SZ;
    float* v = ws + 2 * SZ;
    float* preds = ws + 3 * SZ;
    float* g = ws + 4 * SZ;   // NCHAIN*NCH*4096 = 2M floats (8 MB)
    float* ao = g;            // alias: attn output reuses g (g dead by then)

    proj_gemm<<<dim3(32, 8, 3), 256, 0, stream>>>(x, Wq, Wk, Wv, q, k, v);
    gram_kernel<<<dim3(NCHAIN, NCH), 256, 0, stream>>>(v, g);
    prefix_kernel<<<dim3(256), 256, 0, stream>>>(g);
    invscan<<<dim3(NCHAIN * NCH), 256, 0, stream>>>(g, v, q, lambdas, preds);
    attn_kernel<<<dim3(16, 16), 256, 0, stream>>>(preds, v, k, ao);
    out_gemm<<<dim3(32, 8), 256, 0, stream>>>(ao, Wo, out);
}

// Round 5
// 216.030 us; speedup vs baseline: 6.5951x; 1.3124x over previous
//
#include <hip/hip_runtime.h>

#define T_SEQ 1024
#define DH 64
#define NH 8
#define NB 2
#define EMB 512
#define CS 32       // tokens per scan chunk
#define NCH 32      // scan chunks per chain
#define ACH 16      // attention chunks per chain (64 tokens each)
#define NCHAIN 16   // B*H

__device__ __forceinline__ int swz4(int r, int c4) {
    return r * 16 + ((c4 ^ (r >> 2)) & 15);
}

__device__ __forceinline__ void fma4(float4& o, float s, const float4& b) {
    o.x += s * b.x; o.y += s * b.y; o.z += s * b.z; o.w += s * b.w;
}

// ---------------------------------------------------------------------------
// Stage 1: q/k/v = x @ W{q,k,v}, written as [B,H,T,d] per-head layout.
// ---------------------------------------------------------------------------
__global__ __launch_bounds__(256) void proj_gemm(
    const float* __restrict__ x, const float* __restrict__ Wq,
    const float* __restrict__ Wk, const float* __restrict__ Wv,
    float* __restrict__ q, float* __restrict__ k, float* __restrict__ v) {
    const float* W = (blockIdx.z == 0) ? Wq : (blockIdx.z == 1) ? Wk : Wv;
    float* out = (blockIdx.z == 0) ? q : (blockIdx.z == 1) ? k : v;
    int bm = blockIdx.x, bn = blockIdx.y;
    int tid = threadIdx.x;
    int tx = tid & 15, ty = tid >> 4;

    __shared__ float As[16 * 64];   // [k][m]
    __shared__ float4 Bs[16 * 16];  // [k][n4]

    float4 acc[4];
    acc[0] = acc[1] = acc[2] = acc[3] = make_float4(0.f, 0.f, 0.f, 0.f);

    int ar = tid >> 2, ak4 = tid & 3;
    int bkr = tid >> 4, bn4 = tid & 15;
    const float* Aptr = x + (size_t)(bm * 64 + ar) * EMB + ak4 * 4;
    const float* Bptr = W + (size_t)bkr * EMB + bn * 64 + bn4 * 4;

    for (int k0 = 0; k0 < EMB; k0 += 16) {
        float4 a = *(const float4*)(Aptr + k0);
        float4 b = *(const float4*)(Bptr + (size_t)k0 * EMB);
        __syncthreads();
        As[(ak4 * 4 + 0) * 64 + ar] = a.x;
        As[(ak4 * 4 + 1) * 64 + ar] = a.y;
        As[(ak4 * 4 + 2) * 64 + ar] = a.z;
        As[(ak4 * 4 + 3) * 64 + ar] = a.w;
        Bs[bkr * 16 + bn4] = b;
        __syncthreads();
#pragma unroll
        for (int kk = 0; kk < 16; ++kk) {
            float4 a4 = ((const float4*)As)[kk * 16 + ty];
            float4 b4 = Bs[kk * 16 + tx];
            fma4(acc[0], a4.x, b4);
            fma4(acc[1], a4.y, b4);
            fma4(acc[2], a4.z, b4);
            fma4(acc[3], a4.w, b4);
        }
    }

#pragma unroll
    for (int i = 0; i < 4; ++i) {
        int mm = bm * 64 + ty * 4 + i;
        int bb = mm >> 10, t = mm & 1023;
        float* dst = out + ((size_t)(bb * NH + bn) * T_SEQ + t) * DH + tx * 4;
        *(float4*)dst = acc[i];
    }
}

// ---------------------------------------------------------------------------
// Stage 2a: per-chunk Gram matrices G = X_chunk^T X_chunk (64x64, CS tokens)
// ---------------------------------------------------------------------------
__global__ __launch_bounds__(256) void gram_kernel(
    const float* __restrict__ v, float* __restrict__ g) {
    int chain = blockIdx.x, chunk = blockIdx.y;
    const float* X = v + ((size_t)chain * T_SEQ + chunk * CS) * DH;
    __shared__ float Xs[CS * 64];
    int tid = threadIdx.x;
#pragma unroll
    for (int i = 0; i < (CS * 16) / 256; ++i)
        ((float4*)Xs)[i * 256 + tid] = ((const float4*)X)[i * 256 + tid];
    __syncthreads();

    int tx = tid & 15, ty = tid >> 4;
    float acc[4][4];
#pragma unroll
    for (int i = 0; i < 4; ++i)
#pragma unroll
        for (int j = 0; j < 4; ++j) acc[i][j] = 0.f;

#pragma unroll 4
    for (int t = 0; t < CS; ++t) {
        float a_[4], b_[4];
#pragma unroll
        for (int i = 0; i < 4; ++i) a_[i] = Xs[t * 64 + ty * 4 + i];
#pragma unroll
        for (int j = 0; j < 4; ++j) b_[j] = Xs[t * 64 + tx * 4 + j];
#pragma unroll
        for (int i = 0; i < 4; ++i)
#pragma unroll
            for (int j = 0; j < 4; ++j) acc[i][j] += a_[i] * b_[j];
    }

    float* gp = g + ((size_t)chain * NCH + chunk) * 4096;
#pragma unroll
    for (int i = 0; i < 4; ++i)
        *(float4*)(gp + (ty * 4 + i) * 64 + tx * 4) =
            make_float4(acc[i][0], acc[i][1], acc[i][2], acc[i][3]);
}

// ---------------------------------------------------------------------------
// Stage 2b: in-place EXCLUSIVE prefix sum of Gram matrices over chunks
// ---------------------------------------------------------------------------
__global__ __launch_bounds__(256) void prefix_kernel(float* __restrict__ g) {
    int gid = blockIdx.x * 256 + threadIdx.x;   // 16 chains * 4096 elems
    int chain = gid >> 12, elem = gid & 4095;
    float* p = g + (size_t)chain * NCH * 4096 + elem;
    float run = 0.f;
#pragma unroll
    for (int c = 0; c < NCH; ++c) {
        float val = p[(size_t)c * 4096];
        p[(size_t)c * 4096] = run;
        run += val;
    }
}

// ---------------------------------------------------------------------------
// Stage 2c+2d fused: GJ-invert (lam*I + S) in LDS, then Sherman-Morrison scan.
// 256 threads per matrix: thread = (row = tid>>2, col-chunk = tid&3).
// ---------------------------------------------------------------------------
__global__ __launch_bounds__(256) void invscan(
    const float* __restrict__ g, const float* __restrict__ v,
    const float* __restrict__ q, const float* __restrict__ lambdas,
    float* __restrict__ preds) {
    int blk = blockIdx.x;
    int chain = blk >> 5, chunk = blk & 31;
    int tid = threadIdx.x;
    int row = tid >> 2;       // 0..63
    int ch = tid & 3;         // chunk of 4 float4 slots
    int rsw = row & 15;
    int wav = tid >> 6;       // wave id 0..3
    float lam = lambdas[chain & (NH - 1)];

    __shared__ float Mf[64 * 64];
    __shared__ float Xs[CS * 64];
    __shared__ float Qs[CS * 64];
    __shared__ float hxs[64];
    __shared__ float red1[4], red2[4];
    float4* M4 = (float4*)Mf;

    const float4* gp = (const float4*)(g + (size_t)blk * 4096);
#pragma unroll
    for (int i = 0; i < 4; ++i) {
        int cb = ch * 4 + i;
        M4[row * 16 + (cb ^ rsw)] = gp[row * 16 + cb];
    }
    const float4* vb = (const float4*)(v + ((size_t)chain * T_SEQ + chunk * CS) * DH);
    const float4* qb = (const float4*)(q + ((size_t)chain * T_SEQ + chunk * CS) * DH);
    ((float4*)Xs)[tid] = vb[tid];
    ((float4*)Xs)[256 + tid] = vb[256 + tid];
    ((float4*)Qs)[tid] = qb[tid];
    ((float4*)Qs)[256 + tid] = qb[256 + tid];
    __syncthreads();
    if (ch == (row >> 4))
        Mf[row * 64 + (((row >> 2) ^ rsw) << 2) + (row & 3)] += lam;
    __syncthreads();

    for (int p = 0; p < 64; ++p) {
        int psw = p & 15, pcb = p >> 2, pel = p & 3;
        float gcv = Mf[row * 64 + ((pcb ^ rsw) << 2) + pel];   // M[row][p]
        float piv = Mf[p * 64 + ((pcb ^ psw) << 2) + pel];     // M[p][p]
        float4 own[4], prow[4];
#pragma unroll
        for (int i = 0; i < 4; ++i) {
            int cb = ch * 4 + i;
            own[i] = M4[row * 16 + (cb ^ rsw)];
            prow[i] = M4[p * 16 + (cb ^ psw)];   // uniform -> broadcast
        }
        __syncthreads();
        float ipiv = 1.f / piv;
        bool isp = (row == p);
        float beta = gcv * ipiv;
        float c1 = isp ? 0.f : 1.f;
        float c2 = isp ? ipiv : -beta;
#pragma unroll
        for (int i = 0; i < 4; ++i) {
            int cb = ch * 4 + i;
            float4 o = own[i], pr = prow[i];
            o.x = c1 * o.x + c2 * pr.x;
            o.y = c1 * o.y + c2 * pr.y;
            o.z = c1 * o.z + c2 * pr.z;
            o.w = c1 * o.w + c2 * pr.w;
            M4[row * 16 + (cb ^ rsw)] = o;
        }
        if (ch == (pcb >> 2))
            Mf[row * 64 + ((pcb ^ rsw) << 2) + pel] = isp ? -ipiv : beta;
        __syncthreads();
    }

    float* pb = preds + ((size_t)chain * T_SEQ + chunk * CS) * DH;
    for (int t = 0; t < CS; ++t) {
        float4 mreg[4];
        float hx = 0.f, hq = 0.f;
#pragma unroll
        for (int i = 0; i < 4; ++i) {
            int cb = ch * 4 + i;
            float4 m = M4[row * 16 + (cb ^ rsw)];
            mreg[i] = m;
            float4 x4 = ((const float4*)Xs)[t * 16 + cb];
            float4 q4 = ((const float4*)Qs)[t * 16 + cb];
            hx += m.x * x4.x + m.y * x4.y + m.z * x4.z + m.w * x4.w;
            hq += m.x * q4.x + m.y * q4.y + m.z * q4.z + m.w * q4.w;
        }
        hx += __shfl_xor(hx, 1); hx += __shfl_xor(hx, 2);
        hq += __shfl_xor(hq, 1); hq += __shfl_xor(hq, 2);
        float Hx = -hx, Hq = -hq;

        float xr = Xs[t * 64 + row];
        float qr = Qs[t * 64 + row];
        float s1 = xr * Hx, s2 = qr * Hx;
#pragma unroll
        for (int off = 32; off; off >>= 1) {
            s1 += __shfl_xor(s1, off);
            s2 += __shfl_xor(s2, off);
        }
        if ((tid & 63) == 0) { red1[wav] = s1; red2[wav] = s2; }
        if ((tid & 3) == 0) hxs[row] = Hx;
        __syncthreads();
        float p1 = 0.25f * (red1[0] + red1[1] + red1[2] + red1[3]);
        float p2 = 0.25f * (red2[0] + red2[1] + red2[2] + red2[3]);
        float idn = 1.f / (1.f + p1);
        if ((tid & 3) == 0) pb[(size_t)t * DH + row] = Hq - Hx * (p2 * idn);

        float coef = Hx * idn;
#pragma unroll
        for (int i = 0; i < 4; ++i) {
            int cb = ch * 4 + i;
            float4 m = mreg[i];
            float4 h4 = ((const float4*)hxs)[cb];
            m.x += coef * h4.x; m.y += coef * h4.y;
            m.z += coef * h4.z; m.w += coef * h4.w;
            M4[row * 16 + (cb ^ rsw)] = m;
        }
        __syncthreads();
    }
}

// ---------------------------------------------------------------------------
// Stage 3a: per-64-chunk D_j = V_j^T @ K_j (64x64)
// ---------------------------------------------------------------------------
__global__ __launch_bounds__(256) void kv_gram(
    const float* __restrict__ V, const float* __restrict__ Kv,
    float* __restrict__ D) {
    int chain = blockIdx.x, ck = blockIdx.y;
    __shared__ float Vs[64 * 64];
    __shared__ float Ks2[64 * 64];
    int tid = threadIdx.x;
    const float4* Vb = (const float4*)(V + ((size_t)chain * T_SEQ + ck * 64) * DH);
    const float4* Kb = (const float4*)(Kv + ((size_t)chain * T_SEQ + ck * 64) * DH);
#pragma unroll
    for (int i = 0; i < 4; ++i) {
        ((float4*)Vs)[i * 256 + tid] = Vb[i * 256 + tid];
        ((float4*)Ks2)[i * 256 + tid] = Kb[i * 256 + tid];
    }
    __syncthreads();

    int tx = tid & 15, ty = tid >> 4;
    float acc[4][4];
#pragma unroll
    for (int i = 0; i < 4; ++i)
#pragma unroll
        for (int j = 0; j < 4; ++j) acc[i][j] = 0.f;

#pragma unroll 4
    for (int t = 0; t < 64; ++t) {
        float a_[4], b_[4];
#pragma unroll
        for (int i = 0; i < 4; ++i) a_[i] = Vs[t * 64 + ty * 4 + i];
#pragma unroll
        for (int j = 0; j < 4; ++j) b_[j] = Ks2[t * 64 + tx * 4 + j];
#pragma unroll
        for (int i = 0; i < 4; ++i)
#pragma unroll
            for (int j = 0; j < 4; ++j) acc[i][j] += a_[i] * b_[j];
    }

    float* dp = D + ((size_t)chain * ACH + ck) * 4096;
#pragma unroll
    for (int i = 0; i < 4; ++i)
        *(float4*)(dp + (ty * 4 + i) * 64 + tx * 4) =
            make_float4(acc[i][0], acc[i][1], acc[i][2], acc[i][3]);
}

// ---------------------------------------------------------------------------
// Stage 3b: exclusive prefix over ACH attention chunks
// ---------------------------------------------------------------------------
__global__ __launch_bounds__(256) void kv_prefix(float* __restrict__ d) {
    int gid = blockIdx.x * 256 + threadIdx.x;   // 16 chains * 4096 elems
    int chain = gid >> 12, elem = gid & 4095;
    float* p = d + (size_t)chain * ACH * 4096 + elem;
    float run = 0.f;
#pragma unroll
    for (int c = 0; c < ACH; ++c) {
        float val = p[(size_t)c * 4096];
        p[(size_t)c * 4096] = run;
        run += val;
    }
}

// ---------------------------------------------------------------------------
// Stage 3c: O_i = P_i @ C_i + tril(P_i V_i^T) @ K_i  per (chain, chunk64).
// ---------------------------------------------------------------------------
__global__ __launch_bounds__(256) void attn_chunk(
    const float* __restrict__ P, const float* __restrict__ V,
    const float* __restrict__ Kv, const float* __restrict__ C,
    float* __restrict__ O) {
    int ck = blockIdx.x, bh = blockIdx.y;
    int tid = threadIdx.x, tx = tid & 15, ty = tid >> 4;

    __shared__ float4 Ps[64 * 16];
    __shared__ float4 Bs[64 * 16];   // C, then V, then masked S
    __shared__ float4 Ks[64 * 16];

    int lr = tid >> 2, lc = tid & 3;
    const float4* Pb = (const float4*)(P + ((size_t)bh * T_SEQ + ck * 64) * DH);
    const float4* Vb = (const float4*)(V + ((size_t)bh * T_SEQ + ck * 64) * DH);
    const float4* Kb = (const float4*)(Kv + ((size_t)bh * T_SEQ + ck * 64) * DH);
    const float4* Cb = (const float4*)(C + ((size_t)bh * ACH + ck) * 4096);
#pragma unroll
    for (int i = 0; i < 4; ++i) {
        Ps[swz4(lr, lc + i * 4)] = Pb[lr * 16 + lc + i * 4];
        Bs[swz4(lr, lc + i * 4)] = Cb[lr * 16 + lc + i * 4];
        Ks[swz4(lr, lc + i * 4)] = Kb[lr * 16 + lc + i * 4];
    }

    float4 o[4];
    o[0] = o[1] = o[2] = o[3] = make_float4(0.f, 0.f, 0.f, 0.f);
    __syncthreads();

    const float* Pf = (const float*)Ps;
    // O = P @ C
#pragma unroll 4
    for (int j = 0; j < 64; ++j) {
        float4 b4 = Bs[swz4(j, tx)];
#pragma unroll
        for (int i = 0; i < 4; ++i) {
            float s = Pf[swz4(ty * 4 + i, j >> 2) * 4 + (j & 3)];
            fma4(o[i], s, b4);
        }
    }
    __syncthreads();

    // overwrite C with V
#pragma unroll
    for (int i = 0; i < 4; ++i)
        Bs[swz4(lr, lc + i * 4)] = Vb[lr * 16 + lc + i * 4];
    __syncthreads();

    // S = P @ V^T (registers)
    float4 sa[4][4];
#pragma unroll
    for (int i = 0; i < 4; ++i)
#pragma unroll
        for (int j = 0; j < 4; ++j) sa[i][j] = make_float4(0.f, 0.f, 0.f, 0.f);
#pragma unroll
    for (int d4 = 0; d4 < 16; ++d4) {
        float4 a[4], b[4];
#pragma unroll
        for (int i = 0; i < 4; ++i) a[i] = Ps[swz4(ty * 4 + i, d4)];
#pragma unroll
        for (int j = 0; j < 4; ++j) b[j] = Bs[swz4(tx * 4 + j, d4)];
#pragma unroll
        for (int i = 0; i < 4; ++i)
#pragma unroll
            for (int j = 0; j < 4; ++j) {
                sa[i][j].x += a[i].x * b[j].x;
                sa[i][j].y += a[i].y * b[j].y;
                sa[i][j].z += a[i].z * b[j].z;
                sa[i][j].w += a[i].w * b[j].w;
            }
    }
    __syncthreads();  // all V reads done before overwriting with S

    // masked S -> Bs
#pragma unroll
    for (int i = 0; i < 4; ++i) {
        int m = ty * 4 + i;
        float sv[4];
#pragma unroll
        for (int j = 0; j < 4; ++j) {
            float s = sa[i][j].x + sa[i][j].y + sa[i][j].z + sa[i][j].w;
            if ((tx * 4 + j) > m) s = 0.f;
            sv[j] = s;
        }
        Bs[swz4(m, tx)] = make_float4(sv[0], sv[1], sv[2], sv[3]);
    }
    __syncthreads();

    // O += S @ K
    const float* Sf = (const float*)Bs;
#pragma unroll 4
    for (int j = 0; j < 64; ++j) {
        float4 b4 = Ks[swz4(j, tx)];
#pragma unroll
        for (int i = 0; i < 4; ++i) {
            float s = Sf[swz4(ty * 4 + i, j >> 2) * 4 + (j & 3)];
            fma4(o[i], s, b4);
        }
    }

#pragma unroll
    for (int i = 0; i < 4; ++i) {
        float* dst = O + ((size_t)bh * T_SEQ + ck * 64 + ty * 4 + i) * DH + tx * 4;
        *(float4*)dst = o[i];
    }
}

// ---------------------------------------------------------------------------
// Stage 4: out = mesa_out.reshape(B,T,d*H) @ Wo  (row permutation of Wo).
// ---------------------------------------------------------------------------
__global__ __launch_bounds__(256) void out_gemm(
    const float* __restrict__ A,
    const float* __restrict__ Wo, float* __restrict__ out) {
    int bm = blockIdx.x, bn = blockIdx.y;
    int tid = threadIdx.x;
    int tx = tid & 15, ty = tid >> 4;

    __shared__ float As[16 * 64];
    __shared__ float4 Bs[16 * 16];

    float4 acc[4];
    acc[0] = acc[1] = acc[2] = acc[3] = make_float4(0.f, 0.f, 0.f, 0.f);

    int ar = tid >> 2, ak4 = tid & 3;
    int m_ld = bm * 64 + ar;
    int b_ld = m_ld >> 10, t_ld = m_ld & 1023;
    int bkr = tid >> 4, bn4 = tid & 15;

    for (int bk = 0; bk < 32; ++bk) {
        int kkA = bk * 16 + ak4 * 4;
        int hA = kkA >> 6, ddA = kkA & 63;
        float4 a = *(const float4*)(A + ((size_t)(b_ld * NH + hA) * T_SEQ + t_ld) * DH + ddA);
        int kkB = bk * 16 + bkr;
        int hB = kkB >> 6, ddB = kkB & 63;
        float4 b = *(const float4*)(Wo + (size_t)(ddB * NH + hB) * EMB + bn * 64 + bn4 * 4);
        __syncthreads();
        As[(ak4 * 4 + 0) * 64 + ar] = a.x;
        As[(ak4 * 4 + 1) * 64 + ar] = a.y;
        As[(ak4 * 4 + 2) * 64 + ar] = a.z;
        As[(ak4 * 4 + 3) * 64 + ar] = a.w;
        Bs[bkr * 16 + bn4] = b;
        __syncthreads();
#pragma unroll
        for (int kk = 0; kk < 16; ++kk) {
            float4 a4 = ((const float4*)As)[kk * 16 + ty];
            float4 b4 = Bs[kk * 16 + tx];
            fma4(acc[0], a4.x, b4);
            fma4(acc[1], a4.y, b4);
            fma4(acc[2], a4.z, b4);
            fma4(acc[3], a4.w, b4);
        }
    }

#pragma unroll
    for (int i = 0; i < 4; ++i) {
        float* dst = out + (size_t)(bm * 64 + ty * 4 + i) * EMB + bn * 64 + tx * 4;
        *(float4*)dst = acc[i];
    }
}

extern "C" void kernel_launch(void* const* d_in, const int* in_sizes, int n_in,
                              void* d_out, int out_size, void* d_ws, size_t ws_size,
                              hipStream_t stream) {
    const float* x = (const float*)d_in[0];
    const float* Wq = (const float*)d_in[1];
    const float* Wk = (const float*)d_in[2];
    const float* Wv = (const float*)d_in[3];
    const float* Wo = (const float*)d_in[4];
    const float* lambdas = (const float*)d_in[5];
    float* out = (float*)d_out;

    float* ws = (float*)d_ws;
    const size_t SZ = (size_t)NB * NH * T_SEQ * DH;  // 1048576 floats (4 MB)
    float* q = ws;
    float* k = ws + SZ;
    float* v = ws + 2 * SZ;
    float* preds = ws + 3 * SZ;
    float* g = ws + 4 * SZ;   // 2M floats (8 MB), dead after invscan
    float* dbuf = g;          // alias: 16*16*4096 = 1M floats (4 MB)
    float* ao = g + SZ;       // alias: attn output (4 MB)

    proj_gemm<<<dim3(32, 8, 3), 256, 0, stream>>>(x, Wq, Wk, Wv, q, k, v);
    gram_kernel<<<dim3(NCHAIN, NCH), 256, 0, stream>>>(v, g);
    prefix_kernel<<<dim3(256), 256, 0, stream>>>(g);
    invscan<<<dim3(NCHAIN * NCH), 256, 0, stream>>>(g, v, q, lambdas, preds);
    kv_gram<<<dim3(NCHAIN, ACH), 256, 0, stream>>>(v, k, dbuf);
    kv_prefix<<<dim3(256), 256, 0, stream>>>(dbuf);
    attn_chunk<<<dim3(ACH, NCHAIN), 256, 0, stream>>>(preds, v, k, dbuf, ao);
    out_gemm<<<dim3(32, 8), 256, 0, stream>>>(ao, Wo, out);
}

// Round 6
// 159.815 us; speedup vs baseline: 8.9150x; 1.3518x over previous
//
#include <hip/hip_runtime.h>

#define T_SEQ 1024
#define DH 64
#define NH 8
#define NB 2
#define EMB 512
#define CS 32       // tokens per scan chunk
#define NCH 32      // scan chunks per chain
#define ACH 16      // attention chunks per chain (64 tokens each)
#define NCHAIN 16   // B*H

typedef __attribute__((ext_vector_type(8))) short bf16x8;
typedef __attribute__((ext_vector_type(4))) float f32x4;

__device__ __forceinline__ int swz4(int r, int c4) {
    return r * 16 + ((c4 ^ (r >> 2)) & 15);
}

__device__ __forceinline__ void fma4(float4& o, float s, const float4& b) {
    o.x += s * b.x; o.y += s * b.y; o.z += s * b.z; o.w += s * b.w;
}

__device__ __forceinline__ ushort f2bf(float f) {  // RNE fp32 -> bf16 bits
    unsigned u = __float_as_uint(f);
    return (ushort)((u + 0x7FFFu + ((u >> 16) & 1u)) >> 16);
}
__device__ __forceinline__ float bf2f(ushort h) {
    return __uint_as_float(((unsigned)h) << 16);
}
__device__ __forceinline__ void split2(float f, ushort& hi, ushort& lo) {
    hi = f2bf(f);
    lo = f2bf(f - bf2f(hi));
}

// ---------------------------------------------------------------------------
// Conversion: fp32 array -> bf16 hi/lo pair (vectorized).
// ---------------------------------------------------------------------------
__global__ __launch_bounds__(256) void cvt_split(
    const float4* __restrict__ in, ushort4* __restrict__ hi,
    ushort4* __restrict__ lo) {
    int id = blockIdx.x * 256 + threadIdx.x;
    float4 xv = in[id];
    ushort4 h, l;
    split2(xv.x, h.x, l.x);
    split2(xv.y, h.y, l.y);
    split2(xv.z, h.z, l.z);
    split2(xv.w, h.w, l.w);
    hi[id] = h;
    lo[id] = l;
}

// ---------------------------------------------------------------------------
// Conversion: W [K=512][N=512] -> Wt_hi/lo [N][K] bf16 (transpose + split).
// remap=1 folds the (d,H) interleave: source row = (kk&63)*8 + (kk>>6).
// ---------------------------------------------------------------------------
__global__ __launch_bounds__(256) void cvt_wt(
    const float* __restrict__ W0, const float* __restrict__ W1,
    const float* __restrict__ W2, ushort* __restrict__ dhi,
    ushort* __restrict__ dlo, int remap) {
    int zz = blockIdx.z;
    const float* W = (zz == 0) ? W0 : (zz == 1) ? W1 : W2;
    ushort* hi = dhi + (size_t)zz * 262144;
    ushort* lo = dlo + (size_t)zz * 262144;
    int kk0 = blockIdx.x * 64, n0 = blockIdx.y * 64;
    __shared__ float T[64][65];
    int t = threadIdx.x;
#pragma unroll
    for (int i = 0; i < 4; ++i) {
        int rl = i * 16 + (t >> 4);
        int rs = remap ? (rl * 8 + (kk0 >> 6)) : (kk0 + rl);
        float4 vv = *(const float4*)&W[(size_t)rs * 512 + n0 + (t & 15) * 4];
        T[rl][(t & 15) * 4 + 0] = vv.x;
        T[rl][(t & 15) * 4 + 1] = vv.y;
        T[rl][(t & 15) * 4 + 2] = vv.z;
        T[rl][(t & 15) * 4 + 3] = vv.w;
    }
    __syncthreads();
    int nl = t >> 2, kl = (t & 3) * 16;
#pragma unroll
    for (int j4 = 0; j4 < 4; ++j4) {
        ushort4 h4, l4;
        split2(T[kl + j4 * 4 + 0][nl], h4.x, l4.x);
        split2(T[kl + j4 * 4 + 1][nl], h4.y, l4.y);
        split2(T[kl + j4 * 4 + 2][nl], h4.z, l4.z);
        split2(T[kl + j4 * 4 + 3][nl], h4.w, l4.w);
        size_t dst = (size_t)(n0 + nl) * 512 + kk0 + kl + j4 * 4;
        *(ushort4*)&hi[dst] = h4;
        *(ushort4*)&lo[dst] = l4;
    }
}

// ---------------------------------------------------------------------------
// Conversion: attn-out ao [chain][t][d] -> A2[m=2048][kk=512] hi/lo bf16
// with m = (chain>>3)*1024 + t, kk = (chain&7)*64 + d.
// ---------------------------------------------------------------------------
__global__ __launch_bounds__(256) void cvt_ao(
    const float4* __restrict__ ao, ushort4* __restrict__ hi,
    ushort4* __restrict__ lo) {
    int id = blockIdx.x * 256 + threadIdx.x;   // 262144 float4s
    int chain = id >> 14;
    int tt = (id >> 4) & 1023;
    int d4 = id & 15;
    float4 xv = ao[id];
    int m = ((chain >> 3) << 10) + tt;
    int dst = m * 128 + ((chain & 7) << 4) + d4;   // ushort4 index
    ushort4 h, l;
    split2(xv.x, h.x, l.x);
    split2(xv.y, h.y, l.y);
    split2(xv.z, h.z, l.z);
    split2(xv.w, h.w, l.w);
    hi[dst] = h;
    lo[dst] = l;
}

// ---------------------------------------------------------------------------
// MFMA GEMM: C[M=2048][N=512] = A[M][K=512] * B, A/B as bf16 hi/lo,
// B supplied transposed: Bt[n][k]. acc = Ah*Bh + Ah*Bl + Al*Bh (fp32 acc).
// Block tile 128x64, 4 waves (2x2), wave tile 64x32.
// MODE 0: z picks W & output {q,k,v}, writes [B,H,T,d]. MODE 1: plain [M][N].
// ---------------------------------------------------------------------------
template <int MODE>
__global__ __launch_bounds__(256) void mfma_gemm(
    const ushort* __restrict__ Ahi, const ushort* __restrict__ Alo,
    const ushort* __restrict__ Bth, const ushort* __restrict__ Btl,
    float* __restrict__ o0, float* __restrict__ o1, float* __restrict__ o2) {
    int bm = blockIdx.x, bn = blockIdx.y, zz = blockIdx.z;
    const ushort* Bh = Bth + (size_t)zz * 262144;
    const ushort* Bl = Btl + (size_t)zz * 262144;
    float* out = (MODE == 0) ? ((zz == 0) ? o0 : (zz == 1) ? o1 : o2) : o0;

    __shared__ ushort Ash[128 * 40];
    __shared__ ushort Asl[128 * 40];
    __shared__ ushort Bsh[64 * 40];
    __shared__ ushort Bsl[64 * 40];

    int tid = threadIdx.x;
    int lane = tid & 63, wid = tid >> 6;
    int wm = wid >> 1, wn = wid & 1;
    int fr = lane & 15, fk = (lane >> 4) * 8;
    int sr = tid >> 2, sc = (tid & 3) * 8;

    f32x4 zero = {0.f, 0.f, 0.f, 0.f};
    f32x4 acc[4][2];
#pragma unroll
    for (int f = 0; f < 4; ++f)
#pragma unroll
        for (int g = 0; g < 2; ++g) acc[f][g] = zero;

    const ushort* gAh = Ahi + (size_t)(bm * 128 + sr) * 512 + sc;
    const ushort* gAl = Alo + (size_t)(bm * 128 + sr) * 512 + sc;
    const ushort* gBh = Bh + (size_t)(bn * 64 + sr) * 512 + sc;
    const ushort* gBl = Bl + (size_t)(bn * 64 + sr) * 512 + sc;

    for (int k0 = 0; k0 < 512; k0 += 32) {
        uint4 a0 = *(const uint4*)(gAh + k0);
        uint4 a1 = *(const uint4*)(gAh + 64 * 512 + k0);
        uint4 a2 = *(const uint4*)(gAl + k0);
        uint4 a3 = *(const uint4*)(gAl + 64 * 512 + k0);
        uint4 b0 = *(const uint4*)(gBh + k0);
        uint4 b1 = *(const uint4*)(gBl + k0);
        __syncthreads();
        *(uint4*)&Ash[sr * 40 + sc] = a0;
        *(uint4*)&Ash[(sr + 64) * 40 + sc] = a1;
        *(uint4*)&Asl[sr * 40 + sc] = a2;
        *(uint4*)&Asl[(sr + 64) * 40 + sc] = a3;
        *(uint4*)&Bsh[sr * 40 + sc] = b0;
        *(uint4*)&Bsl[sr * 40 + sc] = b1;
        __syncthreads();
        bf16x8 ah[4], al[4], bh[2], blo[2];
#pragma unroll
        for (int f = 0; f < 4; ++f) {
            int r = wm * 64 + f * 16 + fr;
            ah[f] = *(const bf16x8*)&Ash[r * 40 + fk];
            al[f] = *(const bf16x8*)&Asl[r * 40 + fk];
        }
#pragma unroll
        for (int g = 0; g < 2; ++g) {
            int r = wn * 32 + g * 16 + fr;
            bh[g] = *(const bf16x8*)&Bsh[r * 40 + fk];
            blo[g] = *(const bf16x8*)&Bsl[r * 40 + fk];
        }
#pragma unroll
        for (int f = 0; f < 4; ++f)
#pragma unroll
            for (int g = 0; g < 2; ++g) {
                acc[f][g] = __builtin_amdgcn_mfma_f32_16x16x32_bf16(
                    ah[f], bh[g], acc[f][g], 0, 0, 0);
                acc[f][g] = __builtin_amdgcn_mfma_f32_16x16x32_bf16(
                    ah[f], blo[g], acc[f][g], 0, 0, 0);
                acc[f][g] = __builtin_amdgcn_mfma_f32_16x16x32_bf16(
                    al[f], bh[g], acc[f][g], 0, 0, 0);
            }
    }

    int rbase = (lane >> 4) * 4;
#pragma unroll
    for (int f = 0; f < 4; ++f)
#pragma unroll
        for (int g = 0; g < 2; ++g)
#pragma unroll
            for (int j = 0; j < 4; ++j) {
                int m = bm * 128 + wm * 64 + f * 16 + rbase + j;
                int n = bn * 64 + wn * 32 + g * 16 + (lane & 15);
                float val = acc[f][g][j];
                if (MODE == 0) {
                    int b = m >> 10, tt = m & 1023;
                    int h = n >> 6, d = n & 63;
                    out[(((size_t)(b * 8 + h) * 1024 + tt) << 6) + d] = val;
                } else {
                    out[(size_t)m * 512 + n] = val;
                }
            }
}

// ---------------------------------------------------------------------------
// Stage 2a: per-chunk Gram matrices G = X_chunk^T X_chunk (64x64, CS tokens)
// ---------------------------------------------------------------------------
__global__ __launch_bounds__(256) void gram_kernel(
    const float* __restrict__ v, float* __restrict__ g) {
    int chain = blockIdx.x, chunk = blockIdx.y;
    const float* X = v + ((size_t)chain * T_SEQ + chunk * CS) * DH;
    __shared__ float Xs[CS * 64];
    int tid = threadIdx.x;
#pragma unroll
    for (int i = 0; i < (CS * 16) / 256; ++i)
        ((float4*)Xs)[i * 256 + tid] = ((const float4*)X)[i * 256 + tid];
    __syncthreads();

    int tx = tid & 15, ty = tid >> 4;
    float acc[4][4];
#pragma unroll
    for (int i = 0; i < 4; ++i)
#pragma unroll
        for (int j = 0; j < 4; ++j) acc[i][j] = 0.f;

#pragma unroll 4
    for (int t = 0; t < CS; ++t) {
        float a_[4], b_[4];
#pragma unroll
        for (int i = 0; i < 4; ++i) a_[i] = Xs[t * 64 + ty * 4 + i];
#pragma unroll
        for (int j = 0; j < 4; ++j) b_[j] = Xs[t * 64 + tx * 4 + j];
#pragma unroll
        for (int i = 0; i < 4; ++i)
#pragma unroll
            for (int j = 0; j < 4; ++j) acc[i][j] += a_[i] * b_[j];
    }

    float* gp = g + ((size_t)chain * NCH + chunk) * 4096;
#pragma unroll
    for (int i = 0; i < 4; ++i)
        *(float4*)(gp + (ty * 4 + i) * 64 + tx * 4) =
            make_float4(acc[i][0], acc[i][1], acc[i][2], acc[i][3]);
}

// ---------------------------------------------------------------------------
// Stage 2b: in-place EXCLUSIVE prefix sum of Gram matrices over chunks
// ---------------------------------------------------------------------------
__global__ __launch_bounds__(256) void prefix_kernel(float* __restrict__ g) {
    int gid = blockIdx.x * 256 + threadIdx.x;
    int chain = gid >> 12, elem = gid & 4095;
    float* p = g + (size_t)chain * NCH * 4096 + elem;
    float run = 0.f;
#pragma unroll
    for (int c = 0; c < NCH; ++c) {
        float val = p[(size_t)c * 4096];
        p[(size_t)c * 4096] = run;
        run += val;
    }
}

// ---------------------------------------------------------------------------
// Stage 2c+2d fused: GJ-invert (lam*I + S) in LDS, then Sherman-Morrison scan.
// ---------------------------------------------------------------------------
__global__ __launch_bounds__(256) void invscan(
    const float* __restrict__ g, const float* __restrict__ v,
    const float* __restrict__ q, const float* __restrict__ lambdas,
    float* __restrict__ preds) {
    int blk = blockIdx.x;
    int chain = blk >> 5, chunk = blk & 31;
    int tid = threadIdx.x;
    int row = tid >> 2;
    int ch = tid & 3;
    int rsw = row & 15;
    int wav = tid >> 6;
    float lam = lambdas[chain & (NH - 1)];

    __shared__ float Mf[64 * 64];
    __shared__ float Xs[CS * 64];
    __shared__ float Qs[CS * 64];
    __shared__ float hxs[64];
    __shared__ float red1[4], red2[4];
    float4* M4 = (float4*)Mf;

    const float4* gp = (const float4*)(g + (size_t)blk * 4096);
#pragma unroll
    for (int i = 0; i < 4; ++i) {
        int cb = ch * 4 + i;
        M4[row * 16 + (cb ^ rsw)] = gp[row * 16 + cb];
    }
    const float4* vb = (const float4*)(v + ((size_t)chain * T_SEQ + chunk * CS) * DH);
    const float4* qb = (const float4*)(q + ((size_t)chain * T_SEQ + chunk * CS) * DH);
    ((float4*)Xs)[tid] = vb[tid];
    ((float4*)Xs)[256 + tid] = vb[256 + tid];
    ((float4*)Qs)[tid] = qb[tid];
    ((float4*)Qs)[256 + tid] = qb[256 + tid];
    __syncthreads();
    if (ch == (row >> 4))
        Mf[row * 64 + (((row >> 2) ^ rsw) << 2) + (row & 3)] += lam;
    __syncthreads();

    for (int p = 0; p < 64; ++p) {
        int psw = p & 15, pcb = p >> 2, pel = p & 3;
        float gcv = Mf[row * 64 + ((pcb ^ rsw) << 2) + pel];
        float piv = Mf[p * 64 + ((pcb ^ psw) << 2) + pel];
        float4 own[4], prow[4];
#pragma unroll
        for (int i = 0; i < 4; ++i) {
            int cb = ch * 4 + i;
            own[i] = M4[row * 16 + (cb ^ rsw)];
            prow[i] = M4[p * 16 + (cb ^ psw)];
        }
        __syncthreads();
        float ipiv = 1.f / piv;
        bool isp = (row == p);
        float beta = gcv * ipiv;
        float c1 = isp ? 0.f : 1.f;
        float c2 = isp ? ipiv : -beta;
#pragma unroll
        for (int i = 0; i < 4; ++i) {
            int cb = ch * 4 + i;
            float4 o = own[i], pr = prow[i];
            o.x = c1 * o.x + c2 * pr.x;
            o.y = c1 * o.y + c2 * pr.y;
            o.z = c1 * o.z + c2 * pr.z;
            o.w = c1 * o.w + c2 * pr.w;
            M4[row * 16 + (cb ^ rsw)] = o;
        }
        if (ch == (pcb >> 2))
            Mf[row * 64 + ((pcb ^ rsw) << 2) + pel] = isp ? -ipiv : beta;
        __syncthreads();
    }

    float* pb = preds + ((size_t)chain * T_SEQ + chunk * CS) * DH;
    for (int t = 0; t < CS; ++t) {
        float4 mreg[4];
        float hx = 0.f, hq = 0.f;
#pragma unroll
        for (int i = 0; i < 4; ++i) {
            int cb = ch * 4 + i;
            float4 m = M4[row * 16 + (cb ^ rsw)];
            mreg[i] = m;
            float4 x4 = ((const float4*)Xs)[t * 16 + cb];
            float4 q4 = ((const float4*)Qs)[t * 16 + cb];
            hx += m.x * x4.x + m.y * x4.y + m.z * x4.z + m.w * x4.w;
            hq += m.x * q4.x + m.y * q4.y + m.z * q4.z + m.w * q4.w;
        }
        hx += __shfl_xor(hx, 1); hx += __shfl_xor(hx, 2);
        hq += __shfl_xor(hq, 1); hq += __shfl_xor(hq, 2);
        float Hx = -hx, Hq = -hq;

        float xr = Xs[t * 64 + row];
        float qr = Qs[t * 64 + row];
        float s1 = xr * Hx, s2 = qr * Hx;
#pragma unroll
        for (int off = 32; off; off >>= 1) {
            s1 += __shfl_xor(s1, off);
            s2 += __shfl_xor(s2, off);
        }
        if ((tid & 63) == 0) { red1[wav] = s1; red2[wav] = s2; }
        if ((tid & 3) == 0) hxs[row] = Hx;
        __syncthreads();
        float p1 = 0.25f * (red1[0] + red1[1] + red1[2] + red1[3]);
        float p2 = 0.25f * (red2[0] + red2[1] + red2[2] + red2[3]);
        float idn = 1.f / (1.f + p1);
        if ((tid & 3) == 0) pb[(size_t)t * DH + row] = Hq - Hx * (p2 * idn);

        float coef = Hx * idn;
#pragma unroll
        for (int i = 0; i < 4; ++i) {
            int cb = ch * 4 + i;
            float4 m = mreg[i];
            float4 h4 = ((const float4*)hxs)[cb];
            m.x += coef * h4.x; m.y += coef * h4.y;
            m.z += coef * h4.z; m.w += coef * h4.w;
            M4[row * 16 + (cb ^ rsw)] = m;
        }
        __syncthreads();
    }
}

// ---------------------------------------------------------------------------
// Stage 3a: per-64-chunk D_j = V_j^T @ K_j (64x64)
// ---------------------------------------------------------------------------
__global__ __launch_bounds__(256) void kv_gram(
    const float* __restrict__ V, const float* __restrict__ Kv,
    float* __restrict__ D) {
    int chain = blockIdx.x, ck = blockIdx.y;
    __shared__ float Vs[64 * 64];
    __shared__ float Ks2[64 * 64];
    int tid = threadIdx.x;
    const float4* Vb = (const float4*)(V + ((size_t)chain * T_SEQ + ck * 64) * DH);
    const float4* Kb = (const float4*)(Kv + ((size_t)chain * T_SEQ + ck * 64) * DH);
#pragma unroll
    for (int i = 0; i < 4; ++i) {
        ((float4*)Vs)[i * 256 + tid] = Vb[i * 256 + tid];
        ((float4*)Ks2)[i * 256 + tid] = Kb[i * 256 + tid];
    }
    __syncthreads();

    int tx = tid & 15, ty = tid >> 4;
    float acc[4][4];
#pragma unroll
    for (int i = 0; i < 4; ++i)
#pragma unroll
        for (int j = 0; j < 4; ++j) acc[i][j] = 0.f;

#pragma unroll 4
    for (int t = 0; t < 64; ++t) {
        float a_[4], b_[4];
#pragma unroll
        for (int i = 0; i < 4; ++i) a_[i] = Vs[t * 64 + ty * 4 + i];
#pragma unroll
        for (int j = 0; j < 4; ++j) b_[j] = Ks2[t * 64 + tx * 4 + j];
#pragma unroll
        for (int i = 0; i < 4; ++i)
#pragma unroll
            for (int j = 0; j < 4; ++j) acc[i][j] += a_[i] * b_[j];
    }

    float* dp = D + ((size_t)chain * ACH + ck) * 4096;
#pragma unroll
    for (int i = 0; i < 4; ++i)
        *(float4*)(dp + (ty * 4 + i) * 64 + tx * 4) =
            make_float4(acc[i][0], acc[i][1], acc[i][2], acc[i][3]);
}

// ---------------------------------------------------------------------------
// Stage 3b: exclusive prefix over ACH attention chunks
// ---------------------------------------------------------------------------
__global__ __launch_bounds__(256) void kv_prefix(float* __restrict__ d) {
    int gid = blockIdx.x * 256 + threadIdx.x;
    int chain = gid >> 12, elem = gid & 4095;
    float* p = d + (size_t)chain * ACH * 4096 + elem;
    float run = 0.f;
#pragma unroll
    for (int c = 0; c < ACH; ++c) {
        float val = p[(size_t)c * 4096];
        p[(size_t)c * 4096] = run;
        run += val;
    }
}

// ---------------------------------------------------------------------------
// Stage 3c: O_i = P_i @ C_i + tril(P_i V_i^T) @ K_i  per (chain, chunk64).
// ---------------------------------------------------------------------------
__global__ __launch_bounds__(256) void attn_chunk(
    const float* __restrict__ P, const float* __restrict__ V,
    const float* __restrict__ Kv, const float* __restrict__ C,
    float* __restrict__ O) {
    int ck = blockIdx.x, bh = blockIdx.y;
    int tid = threadIdx.x, tx = tid & 15, ty = tid >> 4;

    __shared__ float4 Ps[64 * 16];
    __shared__ float4 Bs[64 * 16];
    __shared__ float4 Ks[64 * 16];

    int lr = tid >> 2, lc = tid & 3;
    const float4* Pb = (const float4*)(P + ((size_t)bh * T_SEQ + ck * 64) * DH);
    const float4* Vb = (const float4*)(V + ((size_t)bh * T_SEQ + ck * 64) * DH);
    const float4* Kb = (const float4*)(Kv + ((size_t)bh * T_SEQ + ck * 64) * DH);
    const float4* Cb = (const float4*)(C + ((size_t)bh * ACH + ck) * 4096);
#pragma unroll
    for (int i = 0; i < 4; ++i) {
        Ps[swz4(lr, lc + i * 4)] = Pb[lr * 16 + lc + i * 4];
        Bs[swz4(lr, lc + i * 4)] = Cb[lr * 16 + lc + i * 4];
        Ks[swz4(lr, lc + i * 4)] = Kb[lr * 16 + lc + i * 4];
    }

    float4 o[4];
    o[0] = o[1] = o[2] = o[3] = make_float4(0.f, 0.f, 0.f, 0.f);
    __syncthreads();

    const float* Pf = (const float*)Ps;
#pragma unroll 4
    for (int j = 0; j < 64; ++j) {
        float4 b4 = Bs[swz4(j, tx)];
#pragma unroll
        for (int i = 0; i < 4; ++i) {
            float s = Pf[swz4(ty * 4 + i, j >> 2) * 4 + (j & 3)];
            fma4(o[i], s, b4);
        }
    }
    __syncthreads();

#pragma unroll
    for (int i = 0; i < 4; ++i)
        Bs[swz4(lr, lc + i * 4)] = Vb[lr * 16 + lc + i * 4];
    __syncthreads();

    float4 sa[4][4];
#pragma unroll
    for (int i = 0; i < 4; ++i)
#pragma unroll
        for (int j = 0; j < 4; ++j) sa[i][j] = make_float4(0.f, 0.f, 0.f, 0.f);
#pragma unroll
    for (int d4 = 0; d4 < 16; ++d4) {
        float4 a[4], b[4];
#pragma unroll
        for (int i = 0; i < 4; ++i) a[i] = Ps[swz4(ty * 4 + i, d4)];
#pragma unroll
        for (int j = 0; j < 4; ++j) b[j] = Bs[swz4(tx * 4 + j, d4)];
#pragma unroll
        for (int i = 0; i < 4; ++i)
#pragma unroll
            for (int j = 0; j < 4; ++j) {
                sa[i][j].x += a[i].x * b[j].x;
                sa[i][j].y += a[i].y * b[j].y;
                sa[i][j].z += a[i].z * b[j].z;
                sa[i][j].w += a[i].w * b[j].w;
            }
    }
    __syncthreads();

#pragma unroll
    for (int i = 0; i < 4; ++i) {
        int m = ty * 4 + i;
        float sv[4];
#pragma unroll
        for (int j = 0; j < 4; ++j) {
            float s = sa[i][j].x + sa[i][j].y + sa[i][j].z + sa[i][j].w;
            if ((tx * 4 + j) > m) s = 0.f;
            sv[j] = s;
        }
        Bs[swz4(m, tx)] = make_float4(sv[0], sv[1], sv[2], sv[3]);
    }
    __syncthreads();

    const float* Sf = (const float*)Bs;
#pragma unroll 4
    for (int j = 0; j < 64; ++j) {
        float4 b4 = Ks[swz4(j, tx)];
#pragma unroll
        for (int i = 0; i < 4; ++i) {
            float s = Sf[swz4(ty * 4 + i, j >> 2) * 4 + (j & 3)];
            fma4(o[i], s, b4);
        }
    }

#pragma unroll
    for (int i = 0; i < 4; ++i) {
        float* dst = O + ((size_t)bh * T_SEQ + ck * 64 + ty * 4 + i) * DH + tx * 4;
        *(float4*)dst = o[i];
    }
}

extern "C" void kernel_launch(void* const* d_in, const int* in_sizes, int n_in,
                              void* d_out, int out_size, void* d_ws, size_t ws_size,
                              hipStream_t stream) {
    const float* x = (const float*)d_in[0];
    const float* Wq = (const float*)d_in[1];
    const float* Wk = (const float*)d_in[2];
    const float* Wv = (const float*)d_in[3];
    const float* Wo = (const float*)d_in[4];
    const float* lambdas = (const float*)d_in[5];
    float* out = (float*)d_out;

    float* ws = (float*)d_ws;
    const size_t SZ = (size_t)NB * NH * T_SEQ * DH;  // 1048576 floats (4 MB)
    float* q = ws;                 // [0,1M) floats
    float* k = ws + SZ;            // [1M,2M)
    float* v = ws + 2 * SZ;        // [2M,3M)
    // slotD [3M,4M): phase A = x hi/lo; phase B = preds; phase C = A2 hi/lo
    float* preds = ws + 3 * SZ;
    ushort* x_hi = (ushort*)(ws + 3 * SZ);
    ushort* x_lo = (ushort*)(ws + 3 * SZ + SZ / 2);
    ushort* A2_hi = x_hi;
    ushort* A2_lo = x_lo;
    // slotG [4M,6M): phase A = Wt hi/lo; phase B = g; phase C = dbuf+ao;
    //               phase D = Wot hi/lo (+ ao)
    float* g = ws + 4 * SZ;
    ushort* Wt_hi = (ushort*)(ws + 4 * SZ);                 // 768K ushorts
    ushort* Wt_lo = (ushort*)(ws + 4 * SZ + 393216);
    float* dbuf = g;                                        // [4M,5M)
    float* ao = g + SZ;                                     // [5M,6M)
    ushort* Wot_hi = (ushort*)(ws + 4 * SZ);                // 256K ushorts
    ushort* Wot_lo = (ushort*)(ws + 4 * SZ + 131072);

    // 1. split x
    cvt_split<<<dim3(1024), 256, 0, stream>>>(
        (const float4*)x, (ushort4*)x_hi, (ushort4*)x_lo);
    // 2. transpose+split Wq/Wk/Wv
    cvt_wt<<<dim3(8, 8, 3), 256, 0, stream>>>(Wq, Wk, Wv, Wt_hi, Wt_lo, 0);
    // 3. q/k/v projections (MFMA)
    mfma_gemm<0><<<dim3(16, 8, 3), 256, 0, stream>>>(
        x_hi, x_lo, Wt_hi, Wt_lo, q, k, v);
    // 4-6. scan path
    gram_kernel<<<dim3(NCHAIN, NCH), 256, 0, stream>>>(v, g);
    prefix_kernel<<<dim3(256), 256, 0, stream>>>(g);
    invscan<<<dim3(NCHAIN * NCH), 256, 0, stream>>>(g, v, q, lambdas, preds);
    // 7-9. attention path
    kv_gram<<<dim3(NCHAIN, ACH), 256, 0, stream>>>(v, k, dbuf);
    kv_prefix<<<dim3(256), 256, 0, stream>>>(dbuf);
    attn_chunk<<<dim3(ACH, NCHAIN), 256, 0, stream>>>(preds, v, k, dbuf, ao);
    // 10-12. output projection (MFMA)
    cvt_ao<<<dim3(1024), 256, 0, stream>>>(
        (const float4*)ao, (ushort4*)A2_hi, (ushort4*)A2_lo);
    cvt_wt<<<dim3(8, 8, 1), 256, 0, stream>>>(Wo, Wo, Wo, Wot_hi, Wot_lo, 1);
    mfma_gemm<1><<<dim3(16, 8, 1), 256, 0, stream>>>(
        A2_hi, A2_lo, Wot_hi, Wot_lo, out, out, out);
}

// Round 7
// 145.940 us; speedup vs baseline: 9.7625x; 1.0951x over previous
//
#include <hip/hip_runtime.h>

#define T_SEQ 1024
#define DH 64
#define NH 8
#define NB 2
#define EMB 512
#define CS 32       // tokens per scan chunk
#define NCH 32      // scan chunks per chain
#define ACH 16      // attention chunks per chain (64 tokens each)
#define NCHAIN 16   // B*H

typedef __attribute__((ext_vector_type(8))) short bf16x8;
typedef __attribute__((ext_vector_type(4))) float f32x4;

__device__ __forceinline__ int swz4(int r, int c4) {
    return r * 16 + ((c4 ^ (r >> 2)) & 15);
}

__device__ __forceinline__ void fma4(float4& o, float s, const float4& b) {
    o.x += s * b.x; o.y += s * b.y; o.z += s * b.z; o.w += s * b.w;
}

__device__ __forceinline__ ushort f2bf(float f) {  // RNE fp32 -> bf16 bits
    unsigned u = __float_as_uint(f);
    return (ushort)((u + 0x7FFFu + ((u >> 16) & 1u)) >> 16);
}
__device__ __forceinline__ float bf2f(ushort h) {
    return __uint_as_float(((unsigned)h) << 16);
}
__device__ __forceinline__ void split2(float f, ushort& hi, ushort& lo) {
    hi = f2bf(f);
    lo = f2bf(f - bf2f(hi));
}

// ---------------------------------------------------------------------------
// Conversion: fp32 array -> bf16 hi/lo pair (vectorized).
// ---------------------------------------------------------------------------
__global__ __launch_bounds__(256) void cvt_split(
    const float4* __restrict__ in, ushort4* __restrict__ hi,
    ushort4* __restrict__ lo) {
    int id = blockIdx.x * 256 + threadIdx.x;
    float4 xv = in[id];
    ushort4 h, l;
    split2(xv.x, h.x, l.x);
    split2(xv.y, h.y, l.y);
    split2(xv.z, h.z, l.z);
    split2(xv.w, h.w, l.w);
    hi[id] = h;
    lo[id] = l;
}

// ---------------------------------------------------------------------------
// Conversion: W [K=512][N=512] -> Wt_hi/lo [N][K] bf16 (transpose + split).
// remap=1 folds the (d,H) interleave: source row = (kk&63)*8 + (kk>>6).
// ---------------------------------------------------------------------------
__global__ __launch_bounds__(256) void cvt_wt(
    const float* __restrict__ W0, const float* __restrict__ W1,
    const float* __restrict__ W2, ushort* __restrict__ dhi,
    ushort* __restrict__ dlo, int remap) {
    int zz = blockIdx.z;
    const float* W = (zz == 0) ? W0 : (zz == 1) ? W1 : W2;
    ushort* hi = dhi + (size_t)zz * 262144;
    ushort* lo = dlo + (size_t)zz * 262144;
    int kk0 = blockIdx.x * 64, n0 = blockIdx.y * 64;
    __shared__ float T[64][65];
    int t = threadIdx.x;
#pragma unroll
    for (int i = 0; i < 4; ++i) {
        int rl = i * 16 + (t >> 4);
        int rs = remap ? (rl * 8 + (kk0 >> 6)) : (kk0 + rl);
        float4 vv = *(const float4*)&W[(size_t)rs * 512 + n0 + (t & 15) * 4];
        T[rl][(t & 15) * 4 + 0] = vv.x;
        T[rl][(t & 15) * 4 + 1] = vv.y;
        T[rl][(t & 15) * 4 + 2] = vv.z;
        T[rl][(t & 15) * 4 + 3] = vv.w;
    }
    __syncthreads();
    int nl = t >> 2, kl = (t & 3) * 16;
#pragma unroll
    for (int j4 = 0; j4 < 4; ++j4) {
        ushort4 h4, l4;
        split2(T[kl + j4 * 4 + 0][nl], h4.x, l4.x);
        split2(T[kl + j4 * 4 + 1][nl], h4.y, l4.y);
        split2(T[kl + j4 * 4 + 2][nl], h4.z, l4.z);
        split2(T[kl + j4 * 4 + 3][nl], h4.w, l4.w);
        size_t dst = (size_t)(n0 + nl) * 512 + kk0 + kl + j4 * 4;
        *(ushort4*)&hi[dst] = h4;
        *(ushort4*)&lo[dst] = l4;
    }
}

// ---------------------------------------------------------------------------
// Conversion: attn-out ao [chain][t][d] -> A2[m=2048][kk=512] hi/lo bf16
// ---------------------------------------------------------------------------
__global__ __launch_bounds__(256) void cvt_ao(
    const float4* __restrict__ ao, ushort4* __restrict__ hi,
    ushort4* __restrict__ lo) {
    int id = blockIdx.x * 256 + threadIdx.x;   // 262144 float4s
    int chain = id >> 14;
    int tt = (id >> 4) & 1023;
    int d4 = id & 15;
    float4 xv = ao[id];
    int m = ((chain >> 3) << 10) + tt;
    int dst = m * 128 + ((chain & 7) << 4) + d4;   // ushort4 index
    ushort4 h, l;
    split2(xv.x, h.x, l.x);
    split2(xv.y, h.y, l.y);
    split2(xv.z, h.z, l.z);
    split2(xv.w, h.w, l.w);
    hi[dst] = h;
    lo[dst] = l;
}

// ---------------------------------------------------------------------------
// MFMA GEMM: C[M=2048][N=512] = A[M][K=512] * B, A/B as bf16 hi/lo,
// B supplied transposed: Bt[n][k]. acc = Ah*Bh + Ah*Bl + Al*Bh (fp32 acc).
// ---------------------------------------------------------------------------
template <int MODE>
__global__ __launch_bounds__(256) void mfma_gemm(
    const ushort* __restrict__ Ahi, const ushort* __restrict__ Alo,
    const ushort* __restrict__ Bth, const ushort* __restrict__ Btl,
    float* __restrict__ o0, float* __restrict__ o1, float* __restrict__ o2) {
    int bm = blockIdx.x, bn = blockIdx.y, zz = blockIdx.z;
    const ushort* Bh = Bth + (size_t)zz * 262144;
    const ushort* Bl = Btl + (size_t)zz * 262144;
    float* out = (MODE == 0) ? ((zz == 0) ? o0 : (zz == 1) ? o1 : o2) : o0;

    __shared__ ushort Ash[128 * 40];
    __shared__ ushort Asl[128 * 40];
    __shared__ ushort Bsh[64 * 40];
    __shared__ ushort Bsl[64 * 40];

    int tid = threadIdx.x;
    int lane = tid & 63, wid = tid >> 6;
    int wm = wid >> 1, wn = wid & 1;
    int fr = lane & 15, fk = (lane >> 4) * 8;
    int sr = tid >> 2, sc = (tid & 3) * 8;

    f32x4 zero = {0.f, 0.f, 0.f, 0.f};
    f32x4 acc[4][2];
#pragma unroll
    for (int f = 0; f < 4; ++f)
#pragma unroll
        for (int g = 0; g < 2; ++g) acc[f][g] = zero;

    const ushort* gAh = Ahi + (size_t)(bm * 128 + sr) * 512 + sc;
    const ushort* gAl = Alo + (size_t)(bm * 128 + sr) * 512 + sc;
    const ushort* gBh = Bh + (size_t)(bn * 64 + sr) * 512 + sc;
    const ushort* gBl = Bl + (size_t)(bn * 64 + sr) * 512 + sc;

    for (int k0 = 0; k0 < 512; k0 += 32) {
        uint4 a0 = *(const uint4*)(gAh + k0);
        uint4 a1 = *(const uint4*)(gAh + 64 * 512 + k0);
        uint4 a2 = *(const uint4*)(gAl + k0);
        uint4 a3 = *(const uint4*)(gAl + 64 * 512 + k0);
        uint4 b0 = *(const uint4*)(gBh + k0);
        uint4 b1 = *(const uint4*)(gBl + k0);
        __syncthreads();
        *(uint4*)&Ash[sr * 40 + sc] = a0;
        *(uint4*)&Ash[(sr + 64) * 40 + sc] = a1;
        *(uint4*)&Asl[sr * 40 + sc] = a2;
        *(uint4*)&Asl[(sr + 64) * 40 + sc] = a3;
        *(uint4*)&Bsh[sr * 40 + sc] = b0;
        *(uint4*)&Bsl[sr * 40 + sc] = b1;
        __syncthreads();
        bf16x8 ah[4], al[4], bh[2], blo[2];
#pragma unroll
        for (int f = 0; f < 4; ++f) {
            int r = wm * 64 + f * 16 + fr;
            ah[f] = *(const bf16x8*)&Ash[r * 40 + fk];
            al[f] = *(const bf16x8*)&Asl[r * 40 + fk];
        }
#pragma unroll
        for (int g = 0; g < 2; ++g) {
            int r = wn * 32 + g * 16 + fr;
            bh[g] = *(const bf16x8*)&Bsh[r * 40 + fk];
            blo[g] = *(const bf16x8*)&Bsl[r * 40 + fk];
        }
#pragma unroll
        for (int f = 0; f < 4; ++f)
#pragma unroll
            for (int g = 0; g < 2; ++g) {
                acc[f][g] = __builtin_amdgcn_mfma_f32_16x16x32_bf16(
                    ah[f], bh[g], acc[f][g], 0, 0, 0);
                acc[f][g] = __builtin_amdgcn_mfma_f32_16x16x32_bf16(
                    ah[f], blo[g], acc[f][g], 0, 0, 0);
                acc[f][g] = __builtin_amdgcn_mfma_f32_16x16x32_bf16(
                    al[f], bh[g], acc[f][g], 0, 0, 0);
            }
    }

    int rbase = (lane >> 4) * 4;
#pragma unroll
    for (int f = 0; f < 4; ++f)
#pragma unroll
        for (int g = 0; g < 2; ++g)
#pragma unroll
            for (int j = 0; j < 4; ++j) {
                int m = bm * 128 + wm * 64 + f * 16 + rbase + j;
                int n = bn * 64 + wn * 32 + g * 16 + (lane & 15);
                float val = acc[f][g][j];
                if (MODE == 0) {
                    int b = m >> 10, tt = m & 1023;
                    int h = n >> 6, d = n & 63;
                    out[(((size_t)(b * 8 + h) * 1024 + tt) << 6) + d] = val;
                } else {
                    out[(size_t)m * 512 + n] = val;
                }
            }
}

// ---------------------------------------------------------------------------
// Stage 2a: per-chunk Gram matrices G = X_chunk^T X_chunk (64x64, CS tokens)
// ---------------------------------------------------------------------------
__global__ __launch_bounds__(256) void gram_kernel(
    const float* __restrict__ v, float* __restrict__ g) {
    int chain = blockIdx.x, chunk = blockIdx.y;
    const float* X = v + ((size_t)chain * T_SEQ + chunk * CS) * DH;
    __shared__ float Xs[CS * 64];
    int tid = threadIdx.x;
#pragma unroll
    for (int i = 0; i < (CS * 16) / 256; ++i)
        ((float4*)Xs)[i * 256 + tid] = ((const float4*)X)[i * 256 + tid];
    __syncthreads();

    int tx = tid & 15, ty = tid >> 4;
    float acc[4][4];
#pragma unroll
    for (int i = 0; i < 4; ++i)
#pragma unroll
        for (int j = 0; j < 4; ++j) acc[i][j] = 0.f;

#pragma unroll 4
    for (int t = 0; t < CS; ++t) {
        float a_[4], b_[4];
#pragma unroll
        for (int i = 0; i < 4; ++i) a_[i] = Xs[t * 64 + ty * 4 + i];
#pragma unroll
        for (int j = 0; j < 4; ++j) b_[j] = Xs[t * 64 + tx * 4 + j];
#pragma unroll
        for (int i = 0; i < 4; ++i)
#pragma unroll
            for (int j = 0; j < 4; ++j) acc[i][j] += a_[i] * b_[j];
    }

    float* gp = g + ((size_t)chain * NCH + chunk) * 4096;
#pragma unroll
    for (int i = 0; i < 4; ++i)
        *(float4*)(gp + (ty * 4 + i) * 64 + tx * 4) =
            make_float4(acc[i][0], acc[i][1], acc[i][2], acc[i][3]);
}

// ---------------------------------------------------------------------------
// Stage 2b: in-place EXCLUSIVE prefix sum of Gram matrices over chunks
// ---------------------------------------------------------------------------
__global__ __launch_bounds__(256) void prefix_kernel(float* __restrict__ g) {
    int gid = blockIdx.x * 256 + threadIdx.x;
    int chain = gid >> 12, elem = gid & 4095;
    float* p = g + (size_t)chain * NCH * 4096 + elem;
    float run = 0.f;
#pragma unroll
    for (int c = 0; c < NCH; ++c) {
        float val = p[(size_t)c * 4096];
        p[(size_t)c * 4096] = run;
        run += val;
    }
}

// ---------------------------------------------------------------------------
// Stage 2c+2d fused: register-resident GJ sweep + Sherman-Morrison scan.
// Thread = (row = tid>>2, col-chunk ch = tid&3); owns m[16] = M[row][16*ch..]
// in REGISTERS. Symmetric sweep => pivot column == pivot row, so the only
// cross-thread traffic per pivot is the 64-float pivot row (double-buffered
// LDS). One barrier per pivot; one barrier per scan token.
// ---------------------------------------------------------------------------
__global__ __launch_bounds__(256) void invscan(
    const float* __restrict__ g, const float* __restrict__ v,
    const float* __restrict__ q, const float* __restrict__ lambdas,
    float* __restrict__ preds) {
    int blk = blockIdx.x;
    int chain = blk >> 5, chunk = blk & 31;
    int tid = threadIdx.x;
    int row = tid >> 2;       // 0..63
    int ch = tid & 3;         // col chunk (16 cols)
    int wav = tid >> 6;
    float lam = lambdas[chain & (NH - 1)];

    __shared__ float pbuf[2][64];
    __shared__ float Xs[CS * 64];
    __shared__ float Qs[CS * 64];
    __shared__ float hxs[2][64];
    __shared__ float red1[2][4], red2[2][4];

    // ---- load own slice of prefix-Gram into registers (coalesced) ----
    float m[16];
    {
        const float4* gp = (const float4*)(g + (size_t)blk * 4096);
#pragma unroll
        for (int i = 0; i < 4; ++i) {
            float4 t4 = gp[row * 16 + ch * 4 + i];
            m[i * 4 + 0] = t4.x; m[i * 4 + 1] = t4.y;
            m[i * 4 + 2] = t4.z; m[i * 4 + 3] = t4.w;
        }
    }
#pragma unroll
    for (int i = 0; i < 16; ++i)
        if (ch * 16 + i == row) m[i] += lam;   // diagonal

    const float4* vb = (const float4*)(v + ((size_t)chain * T_SEQ + chunk * CS) * DH);
    const float4* qb = (const float4*)(q + ((size_t)chain * T_SEQ + chunk * CS) * DH);
    ((float4*)Xs)[tid] = vb[tid];
    ((float4*)Xs)[256 + tid] = vb[256 + tid];
    ((float4*)Qs)[tid] = qb[tid];
    ((float4*)Qs)[256 + tid] = qb[256 + tid];

    if (row == 0) {
#pragma unroll
        for (int i = 0; i < 16; ++i) pbuf[0][ch * 16 + i] = m[i];
    }
    __syncthreads();

    // ---- GJ sweep: after 64 pivots, regs hold -(lam*I + S)^{-1} ----
    for (int p = 0; p < 64; ++p) {
        const float* pb = pbuf[p & 1];
        float pr[16];
#pragma unroll
        for (int i = 0; i < 4; ++i) {
            float4 t4 = ((const float4*)pb)[ch * 4 + i];
            pr[i * 4 + 0] = t4.x; pr[i * 4 + 1] = t4.y;
            pr[i * 4 + 2] = t4.z; pr[i * 4 + 3] = t4.w;
        }
        float diag = pb[p];        // uniform broadcast
        float gcv = pb[row];       // M[p][row] == M[row][p] (symmetry)
        float ipiv = 1.f / diag;
        if (row == p) {
#pragma unroll
            for (int i = 0; i < 16; ++i)
                m[i] = (ch * 16 + i == p) ? -ipiv : pr[i] * ipiv;
        } else {
            float beta = gcv * ipiv;
#pragma unroll
            for (int i = 0; i < 16; ++i)
                m[i] = (ch * 16 + i == p) ? beta : m[i] - beta * pr[i];
        }
        if (p < 63 && row == p + 1) {
#pragma unroll
            for (int i = 0; i < 16; ++i) pbuf[(p + 1) & 1][ch * 16 + i] = m[i];
        }
        __syncthreads();
    }

    // ---- Sherman-Morrison scan over CS tokens (H = -M, M in regs) ----
    float* pbo = preds + ((size_t)chain * T_SEQ + chunk * CS) * DH;
    for (int t = 0; t < CS; ++t) {
        int par = t & 1;
        float hx = 0.f, hq = 0.f;
#pragma unroll
        for (int i = 0; i < 4; ++i) {
            float4 x4 = ((const float4*)(Xs + t * 64))[ch * 4 + i];  // uniform
            float4 q4 = ((const float4*)(Qs + t * 64))[ch * 4 + i];  // uniform
            hx += m[i * 4 + 0] * x4.x + m[i * 4 + 1] * x4.y +
                  m[i * 4 + 2] * x4.z + m[i * 4 + 3] * x4.w;
            hq += m[i * 4 + 0] * q4.x + m[i * 4 + 1] * q4.y +
                  m[i * 4 + 2] * q4.z + m[i * 4 + 3] * q4.w;
        }
        hx += __shfl_xor(hx, 1); hx += __shfl_xor(hx, 2);
        hq += __shfl_xor(hq, 1); hq += __shfl_xor(hq, 2);
        float Hx = -hx, Hq = -hq;

        float xr = Xs[t * 64 + row];
        float qr = Qs[t * 64 + row];
        float s1 = xr * Hx, s2 = qr * Hx;   // 4x duplicated per row
#pragma unroll
        for (int off = 32; off; off >>= 1) {
            s1 += __shfl_xor(s1, off);
            s2 += __shfl_xor(s2, off);
        }
        if ((tid & 63) == 0) { red1[par][wav] = s1; red2[par][wav] = s2; }
        if (ch == 0) hxs[par][row] = Hx;
        __syncthreads();
        float p1 = 0.25f * (red1[par][0] + red1[par][1] + red1[par][2] + red1[par][3]);
        float p2 = 0.25f * (red2[par][0] + red2[par][1] + red2[par][2] + red2[par][3]);
        float idn = 1.f / (1.f + p1);
        if (ch == 0) pbo[(size_t)t * DH + row] = Hq - Hx * (p2 * idn);

        float coef = Hx * idn;   // H -= coef*Hx[j]  =>  M += coef*Hx[j]
#pragma unroll
        for (int i = 0; i < 4; ++i) {
            float4 h4 = ((const float4*)hxs[par])[ch * 4 + i];  // uniform
            m[i * 4 + 0] += coef * h4.x; m[i * 4 + 1] += coef * h4.y;
            m[i * 4 + 2] += coef * h4.z; m[i * 4 + 3] += coef * h4.w;
        }
    }
}

// ---------------------------------------------------------------------------
// Stage 3a: per-64-chunk D_j = V_j^T @ K_j (64x64)
// ---------------------------------------------------------------------------
__global__ __launch_bounds__(256) void kv_gram(
    const float* __restrict__ V, const float* __restrict__ Kv,
    float* __restrict__ D) {
    int chain = blockIdx.x, ck = blockIdx.y;
    __shared__ float Vs[64 * 64];
    __shared__ float Ks2[64 * 64];
    int tid = threadIdx.x;
    const float4* Vb = (const float4*)(V + ((size_t)chain * T_SEQ + ck * 64) * DH);
    const float4* Kb = (const float4*)(Kv + ((size_t)chain * T_SEQ + ck * 64) * DH);
#pragma unroll
    for (int i = 0; i < 4; ++i) {
        ((float4*)Vs)[i * 256 + tid] = Vb[i * 256 + tid];
        ((float4*)Ks2)[i * 256 + tid] = Kb[i * 256 + tid];
    }
    __syncthreads();

    int tx = tid & 15, ty = tid >> 4;
    float acc[4][4];
#pragma unroll
    for (int i = 0; i < 4; ++i)
#pragma unroll
        for (int j = 0; j < 4; ++j) acc[i][j] = 0.f;

#pragma unroll 4
    for (int t = 0; t < 64; ++t) {
        float a_[4], b_[4];
#pragma unroll
        for (int i = 0; i < 4; ++i) a_[i] = Vs[t * 64 + ty * 4 + i];
#pragma unroll
        for (int j = 0; j < 4; ++j) b_[j] = Ks2[t * 64 + tx * 4 + j];
#pragma unroll
        for (int i = 0; i < 4; ++i)
#pragma unroll
            for (int j = 0; j < 4; ++j) acc[i][j] += a_[i] * b_[j];
    }

    float* dp = D + ((size_t)chain * ACH + ck) * 4096;
#pragma unroll
    for (int i = 0; i < 4; ++i)
        *(float4*)(dp + (ty * 4 + i) * 64 + tx * 4) =
            make_float4(acc[i][0], acc[i][1], acc[i][2], acc[i][3]);
}

// ---------------------------------------------------------------------------
// Stage 3b: exclusive prefix over ACH attention chunks
// ---------------------------------------------------------------------------
__global__ __launch_bounds__(256) void kv_prefix(float* __restrict__ d) {
    int gid = blockIdx.x * 256 + threadIdx.x;
    int chain = gid >> 12, elem = gid & 4095;
    float* p = d + (size_t)chain * ACH * 4096 + elem;
    float run = 0.f;
#pragma unroll
    for (int c = 0; c < ACH; ++c) {
        float val = p[(size_t)c * 4096];
        p[(size_t)c * 4096] = run;
        run += val;
    }
}

// ---------------------------------------------------------------------------
// Stage 3c: O_i = P_i @ C_i + tril(P_i V_i^T) @ K_i  per (chain, chunk64).
// ---------------------------------------------------------------------------
__global__ __launch_bounds__(256) void attn_chunk(
    const float* __restrict__ P, const float* __restrict__ V,
    const float* __restrict__ Kv, const float* __restrict__ C,
    float* __restrict__ O) {
    int ck = blockIdx.x, bh = blockIdx.y;
    int tid = threadIdx.x, tx = tid & 15, ty = tid >> 4;

    __shared__ float4 Ps[64 * 16];
    __shared__ float4 Bs[64 * 16];
    __shared__ float4 Ks[64 * 16];

    int lr = tid >> 2, lc = tid & 3;
    const float4* Pb = (const float4*)(P + ((size_t)bh * T_SEQ + ck * 64) * DH);
    const float4* Vb = (const float4*)(V + ((size_t)bh * T_SEQ + ck * 64) * DH);
    const float4* Kb = (const float4*)(Kv + ((size_t)bh * T_SEQ + ck * 64) * DH);
    const float4* Cb = (const float4*)(C + ((size_t)bh * ACH + ck) * 4096);
#pragma unroll
    for (int i = 0; i < 4; ++i) {
        Ps[swz4(lr, lc + i * 4)] = Pb[lr * 16 + lc + i * 4];
        Bs[swz4(lr, lc + i * 4)] = Cb[lr * 16 + lc + i * 4];
        Ks[swz4(lr, lc + i * 4)] = Kb[lr * 16 + lc + i * 4];
    }

    float4 o[4];
    o[0] = o[1] = o[2] = o[3] = make_float4(0.f, 0.f, 0.f, 0.f);
    __syncthreads();

    const float* Pf = (const float*)Ps;
#pragma unroll 4
    for (int j = 0; j < 64; ++j) {
        float4 b4 = Bs[swz4(j, tx)];
#pragma unroll
        for (int i = 0; i < 4; ++i) {
            float s = Pf[swz4(ty * 4 + i, j >> 2) * 4 + (j & 3)];
            fma4(o[i], s, b4);
        }
    }
    __syncthreads();

#pragma unroll
    for (int i = 0; i < 4; ++i)
        Bs[swz4(lr, lc + i * 4)] = Vb[lr * 16 + lc + i * 4];
    __syncthreads();

    float4 sa[4][4];
#pragma unroll
    for (int i = 0; i < 4; ++i)
#pragma unroll
        for (int j = 0; j < 4; ++j) sa[i][j] = make_float4(0.f, 0.f, 0.f, 0.f);
#pragma unroll
    for (int d4 = 0; d4 < 16; ++d4) {
        float4 a[4], b[4];
#pragma unroll
        for (int i = 0; i < 4; ++i) a[i] = Ps[swz4(ty * 4 + i, d4)];
#pragma unroll
        for (int j = 0; j < 4; ++j) b[j] = Bs[swz4(tx * 4 + j, d4)];
#pragma unroll
        for (int i = 0; i < 4; ++i)
#pragma unroll
            for (int j = 0; j < 4; ++j) {
                sa[i][j].x += a[i].x * b[j].x;
                sa[i][j].y += a[i].y * b[j].y;
                sa[i][j].z += a[i].z * b[j].z;
                sa[i][j].w += a[i].w * b[j].w;
            }
    }
    __syncthreads();

#pragma unroll
    for (int i = 0; i < 4; ++i) {
        int m = ty * 4 + i;
        float sv[4];
#pragma unroll
        for (int j = 0; j < 4; ++j) {
            float s = sa[i][j].x + sa[i][j].y + sa[i][j].z + sa[i][j].w;
            if ((tx * 4 + j) > m) s = 0.f;
            sv[j] = s;
        }
        Bs[swz4(m, tx)] = make_float4(sv[0], sv[1], sv[2], sv[3]);
    }
    __syncthreads();

    const float* Sf = (const float*)Bs;
#pragma unroll 4
    for (int j = 0; j < 64; ++j) {
        float4 b4 = Ks[swz4(j, tx)];
#pragma unroll
        for (int i = 0; i < 4; ++i) {
            float s = Sf[swz4(ty * 4 + i, j >> 2) * 4 + (j & 3)];
            fma4(o[i], s, b4);
        }
    }

#pragma unroll
    for (int i = 0; i < 4; ++i) {
        float* dst = O + ((size_t)bh * T_SEQ + ck * 64 + ty * 4 + i) * DH + tx * 4;
        *(float4*)dst = o[i];
    }
}

extern "C" void kernel_launch(void* const* d_in, const int* in_sizes, int n_in,
                              void* d_out, int out_size, void* d_ws, size_t ws_size,
                              hipStream_t stream) {
    const float* x = (const float*)d_in[0];
    const float* Wq = (const float*)d_in[1];
    const float* Wk = (const float*)d_in[2];
    const float* Wv = (const float*)d_in[3];
    const float* Wo = (const float*)d_in[4];
    const float* lambdas = (const float*)d_in[5];
    float* out = (float*)d_out;

    float* ws = (float*)d_ws;
    const size_t SZ = (size_t)NB * NH * T_SEQ * DH;  // 1048576 floats (4 MB)
    float* q = ws;                 // [0,1M) floats
    float* k = ws + SZ;            // [1M,2M)
    float* v = ws + 2 * SZ;        // [2M,3M)
    float* preds = ws + 3 * SZ;
    ushort* x_hi = (ushort*)(ws + 3 * SZ);
    ushort* x_lo = (ushort*)(ws + 3 * SZ + SZ / 2);
    ushort* A2_hi = x_hi;
    ushort* A2_lo = x_lo;
    float* g = ws + 4 * SZ;
    ushort* Wt_hi = (ushort*)(ws + 4 * SZ);                 // 768K ushorts
    ushort* Wt_lo = (ushort*)(ws + 4 * SZ + 393216);
    float* dbuf = g;                                        // [4M,5M)
    float* ao = g + SZ;                                     // [5M,6M)
    ushort* Wot_hi = (ushort*)(ws + 4 * SZ);                // 256K ushorts
    ushort* Wot_lo = (ushort*)(ws + 4 * SZ + 131072);

    cvt_split<<<dim3(1024), 256, 0, stream>>>(
        (const float4*)x, (ushort4*)x_hi, (ushort4*)x_lo);
    cvt_wt<<<dim3(8, 8, 3), 256, 0, stream>>>(Wq, Wk, Wv, Wt_hi, Wt_lo, 0);
    mfma_gemm<0><<<dim3(16, 8, 3), 256, 0, stream>>>(
        x_hi, x_lo, Wt_hi, Wt_lo, q, k, v);
    gram_kernel<<<dim3(NCHAIN, NCH), 256, 0, stream>>>(v, g);
    prefix_kernel<<<dim3(256), 256, 0, stream>>>(g);
    invscan<<<dim3(NCHAIN * NCH), 256, 0, stream>>>(g, v, q, lambdas, preds);
    kv_gram<<<dim3(NCHAIN, ACH), 256, 0, stream>>>(v, k, dbuf);
    kv_prefix<<<dim3(256), 256, 0, stream>>>(dbuf);
    attn_chunk<<<dim3(ACH, NCHAIN), 256, 0, stream>>>(preds, v, k, dbuf, ao);
    cvt_ao<<<dim3(1024), 256, 0, stream>>>(
        (const float4*)ao, (ushort4*)A2_hi, (ushort4*)A2_lo);
    cvt_wt<<<dim3(8, 8, 1), 256, 0, stream>>>(Wo, Wo, Wo, Wot_hi, Wot_lo, 1);
    mfma_gemm<1><<<dim3(16, 8, 1), 256, 0, stream>>>(
        A2_hi, A2_lo, Wot_hi, Wot_lo, out, out, out);
}